// Round 8
// baseline (331.849 us; speedup 1.0000x reference)
//
#include <hip/hip_runtime.h>
#include <hip/hip_fp16.h>
#include <math.h>

// LatentVoxelGrid: N=65536 pts, M=131072 voxels, K=8 cand, D=64.
// prep  (z->zbf, cursor=0, pack W1z frags; blocks<1024: HBt=f@W1f+b1 MFMA + fbf)
// pair  (MFMA sim MLP + softmax + bucket records, TPW=8, HBt packed loads)
// gather(per-voxel Sum w*f / Sum w -> normalized bf16 msg; msg aliases rec)
// stage2(gate MLP + GRU, bf16 MFMA; no A staging, 75KB LDS -> 2 blocks/CU)

typedef short bf16x8 __attribute__((ext_vector_type(8)));
typedef unsigned short u16x8 __attribute__((ext_vector_type(8)));
typedef float f32x4 __attribute__((ext_vector_type(4)));
#define MFMA __builtin_amdgcn_mfma_f32_16x16x32_bf16
#define CAP 32

__device__ __forceinline__ short f2bf(float f) {  // round-to-nearest-even
  unsigned u = __float_as_uint(f);
  unsigned r = (u + 0x7FFFu + ((u >> 16) & 1u)) >> 16;
  return (short)r;
}

__device__ __forceinline__ float bf2f(unsigned short h) {
  return __uint_as_float(((unsigned)h) << 16);
}

__device__ __forceinline__ float sigm(float x) { return 1.0f / (1.0f + __expf(-x)); }

// ---- prep: zbf, cursor=0, bfZ pack, HBt + fbf (blocks < 1024) ----
__global__ __launch_bounds__(256) void prep_kernel(
    const float* __restrict__ z, const float* __restrict__ f,
    const float* __restrict__ sim_w1, const float* __restrict__ sim_b1,
    unsigned short* __restrict__ zbf, unsigned short* __restrict__ fbf,
    unsigned short* __restrict__ HBt, int* __restrict__ cursor,
    short* __restrict__ bfZ, int M)
{
  long tid = (long)blockIdx.x * 256 + threadIdx.x;
  long nthr = (long)gridDim.x * 256;

  for (long i = tid; i < M; i += nthr) cursor[i] = 0;

  long nz = (long)M * 64;
  for (long i = tid * 8; i < nz; i += nthr * 8) {
    float4 a = *(const float4*)&z[i];
    float4 b4 = *(const float4*)&z[i + 4];
    u16x8 o;
    o[0] = (unsigned short)f2bf(a.x);  o[1] = (unsigned short)f2bf(a.y);
    o[2] = (unsigned short)f2bf(a.z);  o[3] = (unsigned short)f2bf(a.w);
    o[4] = (unsigned short)f2bf(b4.x); o[5] = (unsigned short)f2bf(b4.y);
    o[6] = (unsigned short)f2bf(b4.z); o[7] = (unsigned short)f2bf(b4.w);
    *(u16x8*)&zbf[i] = o;
  }

  if (blockIdx.x == gridDim.x - 1 && threadIdx.x < 64) {
    int lane = threadIdx.x;
    int lr = lane & 15, lg = lane >> 4;
#pragma unroll
    for (int ct = 0; ct < 4; ++ct)
#pragma unroll
      for (int kt = 0; kt < 3; ++kt) {
        bf16x8 b;
#pragma unroll
        for (int e = 0; e < 8; ++e) {
          int k = kt * 32 + lg * 8 + e;  // 0..95: [z(64) | delta(3) | pad]
          float v = (k < 67) ? sim_w1[(64 + k) * 64 + ct * 16 + lr] : 0.0f;
          b[e] = f2bf(v);
        }
        *(bf16x8*)&bfZ[(ct * 3 + kt) * 512 + lane * 8] = b;
      }
  }

  if (blockIdx.x < 1024) {  // hb: wave handles 16 point-rows; also writes fbf
    int wave = blockIdx.x * 4 + (threadIdx.x >> 6);
    int lane = threadIdx.x & 63;
    int lr = lane & 15, lg = lane >> 4;
    int n0 = wave * 16;

    bf16x8 bf[8];  // f-part B frags (sim_w1 is L2-hot)
#pragma unroll
    for (int ct = 0; ct < 4; ++ct)
#pragma unroll
      for (int kt = 0; kt < 2; ++kt) {
        bf16x8 bb;
#pragma unroll
        for (int e = 0; e < 8; ++e)
          bb[e] = f2bf(sim_w1[(kt * 32 + lg * 8 + e) * 64 + ct * 16 + lr]);
        bf[ct * 2 + kt] = bb;
      }

    bf16x8 a[2];
#pragma unroll
    for (int kt = 0; kt < 2; ++kt) {
      const float* src = &f[(long)(n0 + lr) * 64 + kt * 32 + lg * 8];
      float4 v0 = *(const float4*)src;
      float4 v1 = *(const float4*)(src + 4);
      bf16x8 t;
      t[0] = f2bf(v0.x); t[1] = f2bf(v0.y); t[2] = f2bf(v0.z); t[3] = f2bf(v0.w);
      t[4] = f2bf(v1.x); t[5] = f2bf(v1.y); t[6] = f2bf(v1.z); t[7] = f2bf(v1.w);
      a[kt] = t;
    }
    *(bf16x8*)&fbf[(long)(n0 + lr) * 64 + lg * 8] = a[0];
    *(bf16x8*)&fbf[(long)(n0 + lr) * 64 + 32 + lg * 8] = a[1];

    f32x4 acc[4] = {{0,0,0,0},{0,0,0,0},{0,0,0,0},{0,0,0,0}};
#pragma unroll
    for (int ct = 0; ct < 4; ++ct) {
      acc[ct] = MFMA(a[0], bf[ct * 2 + 0], acc[ct], 0, 0, 0);
      acc[ct] = MFMA(a[1], bf[ct * 2 + 1], acc[ct], 0, 0, 0);
    }
    float b10 = sim_b1[lr], b11 = sim_b1[16 + lr];
    float b12 = sim_b1[32 + lr], b13 = sim_b1[48 + lr];
#pragma unroll
    for (int e = 0; e < 4; ++e) {
      // HBt packed: [n][lr*4 + ct] so pair reads hb[0..3] as one 8B load
      unsigned lo = (unsigned)(unsigned short)f2bf(acc[0][e] + b10)
                  | ((unsigned)(unsigned short)f2bf(acc[1][e] + b11) << 16);
      unsigned hi = (unsigned)(unsigned short)f2bf(acc[2][e] + b12)
                  | ((unsigned)(unsigned short)f2bf(acc[3][e] + b13) << 16);
      *(uint2*)&HBt[(long)(n0 + lg * 4 + e) * 64 + lr * 4] = make_uint2(lo, hi);
    }
  }
}

// ---- pair: sim MLP + softmax; TPW=8, 2 records per lane ----
#define TPW 8
__global__ __launch_bounds__(256) void pair_kernel(
    const float* __restrict__ pts, const unsigned short* __restrict__ zbf,
    const float* __restrict__ centers, const int* __restrict__ cand_idx,
    const float* __restrict__ sim_w2, const short* __restrict__ bfZ,
    const unsigned short* __restrict__ HBt,
    int* __restrict__ cursor, unsigned* __restrict__ rec)
{
  int wave = (blockIdx.x * 256 + threadIdx.x) >> 6;
  int lane = threadIdx.x & 63;
  int lr = lane & 15, lg = lane >> 4;

  // this wave owns pairs wave*128..+128; lane owns records lane and 64+lane
  int callA = cand_idx[wave * 128 + lane];
  int callB = cand_idx[wave * 128 + 64 + lane];
  int slotA = atomicAdd(&cursor[callA], 1);  // early; hidden under compute
  int slotB = atomicAdd(&cursor[callB], 1);

  bf16x8 b[12];
#pragma unroll
  for (int i = 0; i < 12; ++i) b[i] = *(const bf16x8*)&bfZ[i * 512 + lane * 8];
  float w2c[4];
#pragma unroll
  for (int ct = 0; ct < 4; ++ct) w2c[ct] = sim_w2[ct * 16 + lr];

  // prologue: tile 0 operand loads
  int c0 = __shfl(callA, lr, 64);
  bf16x8 a0 = *(const bf16x8*)&zbf[(long)c0 * 64 + lg * 8];
  bf16x8 a1 = *(const bf16x8*)&zbf[(long)c0 * 64 + 32 + lg * 8];
  float cx = 0, cy = 0, cz = 0, px = 0, py = 0, pz = 0;
  if (lg == 0) {
    cx = centers[c0 * 3 + 0]; cy = centers[c0 * 3 + 1]; cz = centers[c0 * 3 + 2];
    int n = wave * TPW * 2 + (lr >> 3);
    px = pts[n * 3 + 0]; py = pts[n * 3 + 1]; pz = pts[n * 3 + 2];
  }
  uint2 h2 = *(const uint2*)&HBt[((long)wave * TPW * 2 + (lg >> 1)) * 64 + lr * 4];

  float wst[TPW];  // per-tile stashed weight (valid on lanes 0..15)

#pragma unroll
  for (int t = 0; t < TPW; ++t) {
    // prefetch tile t+1 while computing tile t
    int cn = c0; bf16x8 an0 = a0, an1 = a1;
    float cxn = 0, cyn = 0, czn = 0, pxn = 0, pyn = 0, pzn = 0;
    uint2 h2n = make_uint2(0, 0);
    if (t + 1 < TPW) {
      cn = __shfl((t + 1) < 4 ? callA : callB, ((t + 1) & 3) * 16 + lr, 64);
      an0 = *(const bf16x8*)&zbf[(long)cn * 64 + lg * 8];
      an1 = *(const bf16x8*)&zbf[(long)cn * 64 + 32 + lg * 8];
      if (lg == 0) {
        cxn = centers[cn * 3 + 0]; cyn = centers[cn * 3 + 1]; czn = centers[cn * 3 + 2];
        int n = (wave * TPW + t + 1) * 2 + (lr >> 3);
        pxn = pts[n * 3 + 0]; pyn = pts[n * 3 + 1]; pzn = pts[n * 3 + 2];
      }
      h2n = *(const uint2*)&HBt[((long)(wave * TPW + t + 1) * 2 + (lg >> 1)) * 64 + lr * 4];
    }

    bf16x8 ad = {0, 0, 0, 0, 0, 0, 0, 0};
    if (lg == 0) {
      ad[0] = f2bf(px - cx); ad[1] = f2bf(py - cy); ad[2] = f2bf(pz - cz);
    }

    f32x4 acc[4] = {{0,0,0,0},{0,0,0,0},{0,0,0,0},{0,0,0,0}};
#pragma unroll
    for (int ct = 0; ct < 4; ++ct) {
      acc[ct] = MFMA(a0, b[ct * 3 + 0], acc[ct], 0, 0, 0);
      acc[ct] = MFMA(a1, b[ct * 3 + 1], acc[ct], 0, 0, 0);
      acc[ct] = MFMA(ad, b[ct * 3 + 2], acc[ct], 0, 0, 0);
    }

    float hb[4];
    hb[0] = bf2f((unsigned short)(h2.x));
    hb[1] = bf2f((unsigned short)(h2.x >> 16));
    hb[2] = bf2f((unsigned short)(h2.y));
    hb[3] = bf2f((unsigned short)(h2.y >> 16));

    f32x4 part = {0.f, 0.f, 0.f, 0.f};
#pragma unroll
    for (int ct = 0; ct < 4; ++ct)
#pragma unroll
      for (int e = 0; e < 4; ++e) {
        float u = fmaxf(acc[ct][e] + hb[ct], 0.0f);
        part[e] = fmaf(u, w2c[ct], part[e]);
      }
#pragma unroll
    for (int m = 1; m <= 8; m <<= 1)
#pragma unroll
      for (int e = 0; e < 4; ++e) part[e] += __shfl_xor(part[e], m, 64);

    float other[4];
#pragma unroll
    for (int e = 0; e < 4; ++e) other[e] = __shfl_xor(part[e], 16, 64);

    float mx = part[0];
#pragma unroll
    for (int e = 1; e < 4; ++e) mx = fmaxf(mx, part[e]);
#pragma unroll
    for (int e = 0; e < 4; ++e) mx = fmaxf(mx, other[e]);
    float ex[4], se = 0.f, so = 0.f;
#pragma unroll
    for (int e = 0; e < 4; ++e) {
      ex[e] = __expf((part[e] - mx) * (1.0f / 0.3f));
      se += ex[e];
      so += __expf((other[e] - mx) * (1.0f / 0.3f));
    }
    float inv = 1.0f / (se + so);

    // wst[t] lane r (0..15): weight of MFMA row r (= w[r&3] from lane (r>>2)*16)
    int srcl = (lane >> 2) << 4;
    float t0 = __shfl(ex[0] * inv, srcl, 64);
    float t1 = __shfl(ex[1] * inv, srcl, 64);
    float t2 = __shfl(ex[2] * inv, srcl, 64);
    float t3 = __shfl(ex[3] * inv, srcl, 64);
    int esel = lane & 3;
    wst[t] = esel == 0 ? t0 : esel == 1 ? t1 : esel == 2 ? t2 : t3;

    c0 = cn; a0 = an0; a1 = an1;
    cx = cxn; cy = cyn; cz = czn; px = pxn; py = pyn; pz = pzn;
    h2 = h2n;
  }

  // epilogue: route tile t's row-lr weight to the owning lane
  float v0 = __shfl(wst[0], lr, 64);
  float v1 = __shfl(wst[1], lr, 64);
  float v2 = __shfl(wst[2], lr, 64);
  float v3 = __shfl(wst[3], lr, 64);
  float v4 = __shfl(wst[4], lr, 64);
  float v5 = __shfl(wst[5], lr, 64);
  float v6 = __shfl(wst[6], lr, 64);
  float v7 = __shfl(wst[7], lr, 64);
  float wvA = lg == 0 ? v0 : lg == 1 ? v1 : lg == 2 ? v2 : v3;
  float wvB = lg == 0 ? v4 : lg == 1 ? v5 : lg == 2 ? v6 : v7;

  int base_pt = wave * 16 + 2 * lg + (lr >> 3);
  if (slotA < CAP) {
    unsigned short wh = __half_as_ushort(__float2half(wvA));
    rec[(long)callA * CAP + slotA] = ((unsigned)base_pt << 16) | (unsigned)wh;
  }
  if (slotB < CAP) {
    unsigned short wh = __half_as_ushort(__float2half(wvB));
    rec[(long)callB * CAP + slotB] = ((unsigned)(base_pt + 8) << 16) | (unsigned)wh;
  }
}

// ---- gather: msg[v] = (Sum w*f[n]) / (Sum w + eps); msg ALIASES rec rows ----
__global__ __launch_bounds__(256) void gather_kernel(
    const unsigned* __restrict__ rec, const int* __restrict__ cursor,
    const unsigned short* __restrict__ fbf, unsigned short* __restrict__ msg_bf,
    int mvox)
{
  int tid = blockIdx.x * 256 + threadIdx.x;
  int row = tid >> 2, seg = tid & 3;  // 4 threads per voxel, 16 cols each
  if (row >= mvox) return;

  int cnt = cursor[row];
  cnt = cnt < CAP ? cnt : CAP;
  const unsigned* rp = &rec[(long)row * CAP];

  float acc[16];
#pragma unroll
  for (int j = 0; j < 16; ++j) acc[j] = 0.f;
  float ws = 0.f;

  for (int i0 = 0; i0 < cnt; i0 += 4) {   // rec row chunked 4-wide: fbf loads overlap
    uint4 r4 = *(const uint4*)&rp[i0];
    unsigned rr0 = r4.x, rr1 = r4.y, rr2 = r4.z, rr3 = r4.w;
#pragma unroll
    for (int j = 0; j < 4; ++j) {
      unsigned r = j == 0 ? rr0 : j == 1 ? rr1 : j == 2 ? rr2 : rr3;
      if (i0 + j < cnt) {
        float w = __half2float(__ushort_as_half((unsigned short)(r & 0xffffu)));
        int n = r >> 16;
        ws += w;
        const u16x8* fp = (const u16x8*)&fbf[(long)n * 64 + seg * 16];
        u16x8 f0 = fp[0], f1 = fp[1];
#pragma unroll
        for (int k = 0; k < 8; ++k) {
          acc[k]     = fmaf(w, bf2f(f0[k]), acc[k]);
          acc[8 + k] = fmaf(w, bf2f(f1[k]), acc[8 + k]);
        }
      }
    }
  }
  float inv = 1.0f / (ws + 1e-6f);
  u16x8 o0, o1;
#pragma unroll
  for (int j = 0; j < 8; ++j) {
    o0[j] = (unsigned short)f2bf(acc[j] * inv);
    o1[j] = (unsigned short)f2bf(acc[8 + j] * inv);
  }
  // writes land in this voxel's own (already consumed) rec row
  *(u16x8*)&msg_bf[(long)row * 64 + seg * 16] = o0;
  *(u16x8*)&msg_bf[(long)row * 64 + seg * 16 + 8] = o1;
}

// ---- Stage 2: gate MLP + GRU; no A staging; 75KB LDS -> 2 blocks/CU ----
#define GST 136
#define WST 72

__global__ __launch_bounds__(512, 4) void stage2(
    const unsigned short* __restrict__ zbf,
    const float* __restrict__ gate_w1, const float* __restrict__ gate_b1,
    const float* __restrict__ gate_w2, const float* __restrict__ gate_b2,
    const float* __restrict__ W_ih, const float* __restrict__ W_hh,
    const float* __restrict__ b_ih, const float* __restrict__ b_hh,
    const unsigned short* __restrict__ msg_bf,
    float* __restrict__ out, int ntiles)
{
  __shared__ short G1t[64 * GST];
  __shared__ short Wih_l[192 * WST];
  __shared__ short Whh_l[192 * WST];
  __shared__ float gb1s[64], gw2s[64], bihs[192], bhhs[192];
  __shared__ float gb2s;

  int t = threadIdx.x;
  for (int s = t; s < 64 * 128; s += 512) {
    int j = s & 63, k = s >> 6;
    G1t[j * GST + k] = f2bf(gate_w1[s]);
  }
  for (int s = t; s < 192 * 64; s += 512) {
    int j = s >> 6, k = s & 63;
    Wih_l[j * WST + k] = f2bf(W_ih[s]);
    Whh_l[j * WST + k] = f2bf(W_hh[s]);
  }
  if (t < 64) { gb1s[t] = gate_b1[t]; gw2s[t] = gate_w2[t]; }
  if (t < 192) { bihs[t] = b_ih[t]; bhhs[t] = b_hh[t]; }
  if (t == 0) gb2s = gate_b2[0];
  __syncthreads();

  int wid = t >> 6, lane = t & 63;
  int lr = lane & 15, lg = lane >> 4;

  for (int tile = blockIdx.x; tile < ntiles; tile += gridDim.x) {
    int rowbase = tile * 128 + wid * 16;
    long abase = (long)(rowbase + lr) * 64;
    bf16x8 a[4];
    a[0] = *(const bf16x8*)&zbf[abase + lg * 8];
    a[1] = *(const bf16x8*)&zbf[abase + 32 + lg * 8];
    a[2] = *(const bf16x8*)&msg_bf[abase + lg * 8];
    a[3] = *(const bf16x8*)&msg_bf[abase + 32 + lg * 8];

    f32x4 hnew[4], zs[4];
    f32x4 usum = {0.f, 0.f, 0.f, 0.f};

#pragma unroll
    for (int ct = 0; ct < 4; ++ct) {
      f32x4 au = {0,0,0,0}, air = {0,0,0,0}, aiz = {0,0,0,0}, ain = {0,0,0,0};
      f32x4 ahr = {0,0,0,0}, ahz = {0,0,0,0}, ahn = {0,0,0,0};
#pragma unroll
      for (int kt = 0; kt < 4; ++kt)
        au = MFMA(a[kt], *(const bf16x8*)&G1t[(ct * 16 + lr) * GST + kt * 32 + lg * 8], au, 0, 0, 0);
#pragma unroll
      for (int k2 = 0; k2 < 2; ++k2) {
        bf16x8 amg = a[2 + k2];
        bf16x8 az_ = a[k2];
        int ko = k2 * 32 + lg * 8;
        air = MFMA(amg, *(const bf16x8*)&Wih_l[(      ct * 16 + lr) * WST + ko], air, 0, 0, 0);
        aiz = MFMA(amg, *(const bf16x8*)&Wih_l[( 64 + ct * 16 + lr) * WST + ko], aiz, 0, 0, 0);
        ain = MFMA(amg, *(const bf16x8*)&Wih_l[(128 + ct * 16 + lr) * WST + ko], ain, 0, 0, 0);
        ahr = MFMA(az_, *(const bf16x8*)&Whh_l[(      ct * 16 + lr) * WST + ko], ahr, 0, 0, 0);
        ahz = MFMA(az_, *(const bf16x8*)&Whh_l[( 64 + ct * 16 + lr) * WST + ko], ahz, 0, 0, 0);
        ahn = MFMA(az_, *(const bf16x8*)&Whh_l[(128 + ct * 16 + lr) * WST + ko], ahn, 0, 0, 0);
      }
      int c = ct * 16 + lr;
#pragma unroll
      for (int e = 0; e < 4; ++e) {
        float zv = bf2f(zbf[(long)(rowbase + lg * 4 + e) * 64 + c]);
        zs[ct][e] = zv;
        float uu = fmaxf(au[e] + gb1s[c], 0.0f);
        usum[e] += uu * gw2s[c];
        float rr = sigm(air[e] + bihs[c] + ahr[e] + bhhs[c]);
        float zg = sigm(aiz[e] + bihs[64 + c] + ahz[e] + bhhs[64 + c]);
        float nn = tanhf(ain[e] + bihs[128 + c] + rr * (ahn[e] + bhhs[128 + c]));
        hnew[ct][e] = (1.0f - zg) * nn + zg * zv;
      }
    }

#pragma unroll
    for (int m = 1; m <= 8; m <<= 1)
#pragma unroll
      for (int e = 0; e < 4; ++e) {
        float v = usum[e];
        usum[e] = v + __shfl_xor(v, m, 64);
      }
    float gate[4];
#pragma unroll
    for (int e = 0; e < 4; ++e) gate[e] = sigm(usum[e] + gb2s);

#pragma unroll
    for (int ct = 0; ct < 4; ++ct)
#pragma unroll
      for (int e = 0; e < 4; ++e)
        out[(long)(rowbase + lg * 4 + e) * 64 + ct * 16 + lr] =
            zs[ct][e] + gate[e] * (hnew[ct][e] - zs[ct][e]);
  }
}

extern "C" void kernel_launch(void* const* d_in, const int* in_sizes, int n_in,
                              void* d_out, int out_size, void* d_ws, size_t ws_size,
                              hipStream_t stream) {
  const float* f_pts   = (const float*)d_in[0];
  const float* pts     = (const float*)d_in[1];
  const float* z_lat   = (const float*)d_in[2];
  const float* centers = (const float*)d_in[3];
  const int*   cand    = (const int*)d_in[4];
  const float* sim_w1  = (const float*)d_in[5];
  const float* sim_b1  = (const float*)d_in[6];
  const float* sim_w2  = (const float*)d_in[7];
  // d_in[8] = sim_b2: uniform softmax shift, unused
  const float* gate_w1 = (const float*)d_in[9];
  const float* gate_b1 = (const float*)d_in[10];
  const float* gate_w2 = (const float*)d_in[11];
  const float* gate_b2 = (const float*)d_in[12];
  const float* W_ih    = (const float*)d_in[13];
  const float* W_hh    = (const float*)d_in[14];
  const float* b_ih    = (const float*)d_in[15];
  const float* b_hh    = (const float*)d_in[16];

  int N = in_sizes[0] / 64;
  int M = in_sizes[2] / 64;

  int* cursor = (int*)d_ws;                                        // M i32
  unsigned* rec = (unsigned*)(cursor + M);                         // M*CAP u32
  unsigned short* msg_bf = (unsigned short*)rec;                   // alias: rec consumed by gather
  unsigned short* zbf = (unsigned short*)(rec + (size_t)M * CAP);  // M*64 bf16 (live thru stage2)
  unsigned short* fbf = zbf + (size_t)M * 64;                      // N*64 bf16
  unsigned short* HBt = fbf + (size_t)N * 64;                      // N*64 bf16 (transposed ct-packed)
  short* bfZ = (short*)(HBt + (size_t)N * 64);                     // 12*512 bf16

  prep_kernel<<<2048, 256, 0, stream>>>(z_lat, f_pts, sim_w1, sim_b1,
                                        zbf, fbf, HBt, cursor, bfZ, M);

  int nwaves = (N * 8) / (16 * TPW);                               // 4096 waves
  pair_kernel<<<nwaves / 4, 256, 0, stream>>>(pts, zbf, centers, cand,
                                              sim_w2, bfZ, HBt, cursor, rec);

  gather_kernel<<<(M * 4) / 256, 256, 0, stream>>>(rec, cursor, fbf, msg_bf, M);

  int ntiles = M / 128;
  stage2<<<512, 512, 0, stream>>>(zbf, gate_w1, gate_b1, gate_w2, gate_b2,
                                  W_ih, W_hh, b_ih, b_hh, msg_bf,
                                  (float*)d_out, ntiles);
}

// Round 9
// 191.167 us; speedup vs baseline: 1.7359x; 1.7359x over previous
//
#include <hip/hip_runtime.h>
#include <hip/hip_fp16.h>
#include <math.h>

// LatentVoxelGrid: N=65536 pts, M=131072 voxels, K=8 cand, D=64.
// prep  (z->zbf, cursor=0, pack W1z frags; blocks<1024: HBt=f@W1f+b1 MFMA + fbf)
// pair  (MFMA sim MLP + softmax + bucket records, TPW=8, HBt packed loads)
// gather(per-voxel Sum w*f / Sum w -> normalized bf16 msg; msg aliases rec)
// stage2(gate MLP + GRU, bf16 MFMA; no A staging, 75KB LDS, NO min-occupancy cap)

typedef short bf16x8 __attribute__((ext_vector_type(8)));
typedef unsigned short u16x8 __attribute__((ext_vector_type(8)));
typedef float f32x4 __attribute__((ext_vector_type(4)));
#define MFMA __builtin_amdgcn_mfma_f32_16x16x32_bf16
#define CAP 32

__device__ __forceinline__ short f2bf(float f) {  // round-to-nearest-even
  unsigned u = __float_as_uint(f);
  unsigned r = (u + 0x7FFFu + ((u >> 16) & 1u)) >> 16;
  return (short)r;
}

__device__ __forceinline__ float bf2f(unsigned short h) {
  return __uint_as_float(((unsigned)h) << 16);
}

__device__ __forceinline__ float sigm(float x) { return 1.0f / (1.0f + __expf(-x)); }

// ---- prep: zbf, cursor=0, bfZ pack, HBt + fbf (blocks < 1024) ----
__global__ __launch_bounds__(256) void prep_kernel(
    const float* __restrict__ z, const float* __restrict__ f,
    const float* __restrict__ sim_w1, const float* __restrict__ sim_b1,
    unsigned short* __restrict__ zbf, unsigned short* __restrict__ fbf,
    unsigned short* __restrict__ HBt, int* __restrict__ cursor,
    short* __restrict__ bfZ, int M)
{
  long tid = (long)blockIdx.x * 256 + threadIdx.x;
  long nthr = (long)gridDim.x * 256;

  for (long i = tid; i < M; i += nthr) cursor[i] = 0;

  long nz = (long)M * 64;
  for (long i = tid * 8; i < nz; i += nthr * 8) {
    float4 a = *(const float4*)&z[i];
    float4 b4 = *(const float4*)&z[i + 4];
    u16x8 o;
    o[0] = (unsigned short)f2bf(a.x);  o[1] = (unsigned short)f2bf(a.y);
    o[2] = (unsigned short)f2bf(a.z);  o[3] = (unsigned short)f2bf(a.w);
    o[4] = (unsigned short)f2bf(b4.x); o[5] = (unsigned short)f2bf(b4.y);
    o[6] = (unsigned short)f2bf(b4.z); o[7] = (unsigned short)f2bf(b4.w);
    *(u16x8*)&zbf[i] = o;
  }

  if (blockIdx.x == gridDim.x - 1 && threadIdx.x < 64) {
    int lane = threadIdx.x;
    int lr = lane & 15, lg = lane >> 4;
#pragma unroll
    for (int ct = 0; ct < 4; ++ct)
#pragma unroll
      for (int kt = 0; kt < 3; ++kt) {
        bf16x8 b;
#pragma unroll
        for (int e = 0; e < 8; ++e) {
          int k = kt * 32 + lg * 8 + e;  // 0..95: [z(64) | delta(3) | pad]
          float v = (k < 67) ? sim_w1[(64 + k) * 64 + ct * 16 + lr] : 0.0f;
          b[e] = f2bf(v);
        }
        *(bf16x8*)&bfZ[(ct * 3 + kt) * 512 + lane * 8] = b;
      }
  }

  if (blockIdx.x < 1024) {  // hb: wave handles 16 point-rows; also writes fbf
    int wave = blockIdx.x * 4 + (threadIdx.x >> 6);
    int lane = threadIdx.x & 63;
    int lr = lane & 15, lg = lane >> 4;
    int n0 = wave * 16;

    bf16x8 bf[8];  // f-part B frags (sim_w1 is L2-hot)
#pragma unroll
    for (int ct = 0; ct < 4; ++ct)
#pragma unroll
      for (int kt = 0; kt < 2; ++kt) {
        bf16x8 bb;
#pragma unroll
        for (int e = 0; e < 8; ++e)
          bb[e] = f2bf(sim_w1[(kt * 32 + lg * 8 + e) * 64 + ct * 16 + lr]);
        bf[ct * 2 + kt] = bb;
      }

    bf16x8 a[2];
#pragma unroll
    for (int kt = 0; kt < 2; ++kt) {
      const float* src = &f[(long)(n0 + lr) * 64 + kt * 32 + lg * 8];
      float4 v0 = *(const float4*)src;
      float4 v1 = *(const float4*)(src + 4);
      bf16x8 t;
      t[0] = f2bf(v0.x); t[1] = f2bf(v0.y); t[2] = f2bf(v0.z); t[3] = f2bf(v0.w);
      t[4] = f2bf(v1.x); t[5] = f2bf(v1.y); t[6] = f2bf(v1.z); t[7] = f2bf(v1.w);
      a[kt] = t;
    }
    *(bf16x8*)&fbf[(long)(n0 + lr) * 64 + lg * 8] = a[0];
    *(bf16x8*)&fbf[(long)(n0 + lr) * 64 + 32 + lg * 8] = a[1];

    f32x4 acc[4] = {{0,0,0,0},{0,0,0,0},{0,0,0,0},{0,0,0,0}};
#pragma unroll
    for (int ct = 0; ct < 4; ++ct) {
      acc[ct] = MFMA(a[0], bf[ct * 2 + 0], acc[ct], 0, 0, 0);
      acc[ct] = MFMA(a[1], bf[ct * 2 + 1], acc[ct], 0, 0, 0);
    }
    float b10 = sim_b1[lr], b11 = sim_b1[16 + lr];
    float b12 = sim_b1[32 + lr], b13 = sim_b1[48 + lr];
#pragma unroll
    for (int e = 0; e < 4; ++e) {
      // HBt packed: [n][lr*4 + ct] so pair reads hb[0..3] as one 8B load
      unsigned lo = (unsigned)(unsigned short)f2bf(acc[0][e] + b10)
                  | ((unsigned)(unsigned short)f2bf(acc[1][e] + b11) << 16);
      unsigned hi = (unsigned)(unsigned short)f2bf(acc[2][e] + b12)
                  | ((unsigned)(unsigned short)f2bf(acc[3][e] + b13) << 16);
      *(uint2*)&HBt[(long)(n0 + lg * 4 + e) * 64 + lr * 4] = make_uint2(lo, hi);
    }
  }
}

// ---- pair: sim MLP + softmax; TPW=8, 2 records per lane ----
#define TPW 8
__global__ __launch_bounds__(256) void pair_kernel(
    const float* __restrict__ pts, const unsigned short* __restrict__ zbf,
    const float* __restrict__ centers, const int* __restrict__ cand_idx,
    const float* __restrict__ sim_w2, const short* __restrict__ bfZ,
    const unsigned short* __restrict__ HBt,
    int* __restrict__ cursor, unsigned* __restrict__ rec)
{
  int wave = (blockIdx.x * 256 + threadIdx.x) >> 6;
  int lane = threadIdx.x & 63;
  int lr = lane & 15, lg = lane >> 4;

  // this wave owns pairs wave*128..+128; lane owns records lane and 64+lane
  int callA = cand_idx[wave * 128 + lane];
  int callB = cand_idx[wave * 128 + 64 + lane];
  int slotA = atomicAdd(&cursor[callA], 1);  // early; hidden under compute
  int slotB = atomicAdd(&cursor[callB], 1);

  bf16x8 b[12];
#pragma unroll
  for (int i = 0; i < 12; ++i) b[i] = *(const bf16x8*)&bfZ[i * 512 + lane * 8];
  float w2c[4];
#pragma unroll
  for (int ct = 0; ct < 4; ++ct) w2c[ct] = sim_w2[ct * 16 + lr];

  // prologue: tile 0 operand loads
  int c0 = __shfl(callA, lr, 64);
  bf16x8 a0 = *(const bf16x8*)&zbf[(long)c0 * 64 + lg * 8];
  bf16x8 a1 = *(const bf16x8*)&zbf[(long)c0 * 64 + 32 + lg * 8];
  float cx = 0, cy = 0, cz = 0, px = 0, py = 0, pz = 0;
  if (lg == 0) {
    cx = centers[c0 * 3 + 0]; cy = centers[c0 * 3 + 1]; cz = centers[c0 * 3 + 2];
    int n = wave * TPW * 2 + (lr >> 3);
    px = pts[n * 3 + 0]; py = pts[n * 3 + 1]; pz = pts[n * 3 + 2];
  }
  uint2 h2 = *(const uint2*)&HBt[((long)wave * TPW * 2 + (lg >> 1)) * 64 + lr * 4];

  float wst[TPW];  // per-tile stashed weight (valid on lanes 0..15)

#pragma unroll
  for (int t = 0; t < TPW; ++t) {
    // prefetch tile t+1 while computing tile t
    int cn = c0; bf16x8 an0 = a0, an1 = a1;
    float cxn = 0, cyn = 0, czn = 0, pxn = 0, pyn = 0, pzn = 0;
    uint2 h2n = make_uint2(0, 0);
    if (t + 1 < TPW) {
      cn = __shfl((t + 1) < 4 ? callA : callB, ((t + 1) & 3) * 16 + lr, 64);
      an0 = *(const bf16x8*)&zbf[(long)cn * 64 + lg * 8];
      an1 = *(const bf16x8*)&zbf[(long)cn * 64 + 32 + lg * 8];
      if (lg == 0) {
        cxn = centers[cn * 3 + 0]; cyn = centers[cn * 3 + 1]; czn = centers[cn * 3 + 2];
        int n = (wave * TPW + t + 1) * 2 + (lr >> 3);
        pxn = pts[n * 3 + 0]; pyn = pts[n * 3 + 1]; pzn = pts[n * 3 + 2];
      }
      h2n = *(const uint2*)&HBt[((long)(wave * TPW + t + 1) * 2 + (lg >> 1)) * 64 + lr * 4];
    }

    bf16x8 ad = {0, 0, 0, 0, 0, 0, 0, 0};
    if (lg == 0) {
      ad[0] = f2bf(px - cx); ad[1] = f2bf(py - cy); ad[2] = f2bf(pz - cz);
    }

    f32x4 acc[4] = {{0,0,0,0},{0,0,0,0},{0,0,0,0},{0,0,0,0}};
#pragma unroll
    for (int ct = 0; ct < 4; ++ct) {
      acc[ct] = MFMA(a0, b[ct * 3 + 0], acc[ct], 0, 0, 0);
      acc[ct] = MFMA(a1, b[ct * 3 + 1], acc[ct], 0, 0, 0);
      acc[ct] = MFMA(ad, b[ct * 3 + 2], acc[ct], 0, 0, 0);
    }

    float hb[4];
    hb[0] = bf2f((unsigned short)(h2.x));
    hb[1] = bf2f((unsigned short)(h2.x >> 16));
    hb[2] = bf2f((unsigned short)(h2.y));
    hb[3] = bf2f((unsigned short)(h2.y >> 16));

    f32x4 part = {0.f, 0.f, 0.f, 0.f};
#pragma unroll
    for (int ct = 0; ct < 4; ++ct)
#pragma unroll
      for (int e = 0; e < 4; ++e) {
        float u = fmaxf(acc[ct][e] + hb[ct], 0.0f);
        part[e] = fmaf(u, w2c[ct], part[e]);
      }
#pragma unroll
    for (int m = 1; m <= 8; m <<= 1)
#pragma unroll
      for (int e = 0; e < 4; ++e) part[e] += __shfl_xor(part[e], m, 64);

    float other[4];
#pragma unroll
    for (int e = 0; e < 4; ++e) other[e] = __shfl_xor(part[e], 16, 64);

    float mx = part[0];
#pragma unroll
    for (int e = 1; e < 4; ++e) mx = fmaxf(mx, part[e]);
#pragma unroll
    for (int e = 0; e < 4; ++e) mx = fmaxf(mx, other[e]);
    float ex[4], se = 0.f, so = 0.f;
#pragma unroll
    for (int e = 0; e < 4; ++e) {
      ex[e] = __expf((part[e] - mx) * (1.0f / 0.3f));
      se += ex[e];
      so += __expf((other[e] - mx) * (1.0f / 0.3f));
    }
    float inv = 1.0f / (se + so);

    // wst[t] lane r (0..15): weight of MFMA row r (= w[r&3] from lane (r>>2)*16)
    int srcl = (lane >> 2) << 4;
    float t0 = __shfl(ex[0] * inv, srcl, 64);
    float t1 = __shfl(ex[1] * inv, srcl, 64);
    float t2 = __shfl(ex[2] * inv, srcl, 64);
    float t3 = __shfl(ex[3] * inv, srcl, 64);
    int esel = lane & 3;
    wst[t] = esel == 0 ? t0 : esel == 1 ? t1 : esel == 2 ? t2 : t3;

    c0 = cn; a0 = an0; a1 = an1;
    cx = cxn; cy = cyn; cz = czn; px = pxn; py = pyn; pz = pzn;
    h2 = h2n;
  }

  // epilogue: route tile t's row-lr weight to the owning lane
  float v0 = __shfl(wst[0], lr, 64);
  float v1 = __shfl(wst[1], lr, 64);
  float v2 = __shfl(wst[2], lr, 64);
  float v3 = __shfl(wst[3], lr, 64);
  float v4 = __shfl(wst[4], lr, 64);
  float v5 = __shfl(wst[5], lr, 64);
  float v6 = __shfl(wst[6], lr, 64);
  float v7 = __shfl(wst[7], lr, 64);
  float wvA = lg == 0 ? v0 : lg == 1 ? v1 : lg == 2 ? v2 : v3;
  float wvB = lg == 0 ? v4 : lg == 1 ? v5 : lg == 2 ? v6 : v7;

  int base_pt = wave * 16 + 2 * lg + (lr >> 3);
  if (slotA < CAP) {
    unsigned short wh = __half_as_ushort(__float2half(wvA));
    rec[(long)callA * CAP + slotA] = ((unsigned)base_pt << 16) | (unsigned)wh;
  }
  if (slotB < CAP) {
    unsigned short wh = __half_as_ushort(__float2half(wvB));
    rec[(long)callB * CAP + slotB] = ((unsigned)(base_pt + 8) << 16) | (unsigned)wh;
  }
}

// ---- gather: msg[v] = (Sum w*f[n]) / (Sum w + eps); msg ALIASES rec rows ----
__global__ __launch_bounds__(256) void gather_kernel(
    const unsigned* __restrict__ rec, const int* __restrict__ cursor,
    const unsigned short* __restrict__ fbf, unsigned short* __restrict__ msg_bf,
    int mvox)
{
  int tid = blockIdx.x * 256 + threadIdx.x;
  int row = tid >> 2, seg = tid & 3;  // 4 threads per voxel, 16 cols each
  if (row >= mvox) return;

  int cnt = cursor[row];
  cnt = cnt < CAP ? cnt : CAP;
  const unsigned* rp = &rec[(long)row * CAP];

  float acc[16];
#pragma unroll
  for (int j = 0; j < 16; ++j) acc[j] = 0.f;
  float ws = 0.f;

  for (int i0 = 0; i0 < cnt; i0 += 4) {   // rec row chunked 4-wide: fbf loads overlap
    uint4 r4 = *(const uint4*)&rp[i0];
    unsigned rr0 = r4.x, rr1 = r4.y, rr2 = r4.z, rr3 = r4.w;
#pragma unroll
    for (int j = 0; j < 4; ++j) {
      unsigned r = j == 0 ? rr0 : j == 1 ? rr1 : j == 2 ? rr2 : rr3;
      if (i0 + j < cnt) {
        float w = __half2float(__ushort_as_half((unsigned short)(r & 0xffffu)));
        int n = r >> 16;
        ws += w;
        const u16x8* fp = (const u16x8*)&fbf[(long)n * 64 + seg * 16];
        u16x8 f0 = fp[0], f1 = fp[1];
#pragma unroll
        for (int k = 0; k < 8; ++k) {
          acc[k]     = fmaf(w, bf2f(f0[k]), acc[k]);
          acc[8 + k] = fmaf(w, bf2f(f1[k]), acc[8 + k]);
        }
      }
    }
  }
  float inv = 1.0f / (ws + 1e-6f);
  u16x8 o0, o1;
#pragma unroll
  for (int j = 0; j < 8; ++j) {
    o0[j] = (unsigned short)f2bf(acc[j] * inv);
    o1[j] = (unsigned short)f2bf(acc[8 + j] * inv);
  }
  // writes land in this voxel's own (already consumed) rec row
  *(u16x8*)&msg_bf[(long)row * 64 + seg * 16] = o0;
  *(u16x8*)&msg_bf[(long)row * 64 + seg * 16 + 8] = o1;
}

// ---- Stage 2: gate MLP + GRU; no A staging; 75KB LDS; natural occupancy ----
#define GST 136
#define WST 72

__global__ __launch_bounds__(512) void stage2(
    const unsigned short* __restrict__ zbf,
    const float* __restrict__ gate_w1, const float* __restrict__ gate_b1,
    const float* __restrict__ gate_w2, const float* __restrict__ gate_b2,
    const float* __restrict__ W_ih, const float* __restrict__ W_hh,
    const float* __restrict__ b_ih, const float* __restrict__ b_hh,
    const unsigned short* __restrict__ msg_bf,
    float* __restrict__ out, int ntiles)
{
  __shared__ short G1t[64 * GST];
  __shared__ short Wih_l[192 * WST];
  __shared__ short Whh_l[192 * WST];
  __shared__ float gb1s[64], gw2s[64], bihs[192], bhhs[192];
  __shared__ float gb2s;

  int t = threadIdx.x;
  for (int s = t; s < 64 * 128; s += 512) {
    int j = s & 63, k = s >> 6;
    G1t[j * GST + k] = f2bf(gate_w1[s]);
  }
  for (int s = t; s < 192 * 64; s += 512) {
    int j = s >> 6, k = s & 63;
    Wih_l[j * WST + k] = f2bf(W_ih[s]);
    Whh_l[j * WST + k] = f2bf(W_hh[s]);
  }
  if (t < 64) { gb1s[t] = gate_b1[t]; gw2s[t] = gate_w2[t]; }
  if (t < 192) { bihs[t] = b_ih[t]; bhhs[t] = b_hh[t]; }
  if (t == 0) gb2s = gate_b2[0];
  __syncthreads();

  int wid = t >> 6, lane = t & 63;
  int lr = lane & 15, lg = lane >> 4;

  for (int tile = blockIdx.x; tile < ntiles; tile += gridDim.x) {
    int rowbase = tile * 128 + wid * 16;
    long abase = (long)(rowbase + lr) * 64;
    bf16x8 a[4];
    a[0] = *(const bf16x8*)&zbf[abase + lg * 8];
    a[1] = *(const bf16x8*)&zbf[abase + 32 + lg * 8];
    a[2] = *(const bf16x8*)&msg_bf[abase + lg * 8];
    a[3] = *(const bf16x8*)&msg_bf[abase + 32 + lg * 8];

    f32x4 hnew[4], zs[4];
    f32x4 usum = {0.f, 0.f, 0.f, 0.f};

#pragma unroll
    for (int ct = 0; ct < 4; ++ct) {
      f32x4 au = {0,0,0,0}, air = {0,0,0,0}, aiz = {0,0,0,0}, ain = {0,0,0,0};
      f32x4 ahr = {0,0,0,0}, ahz = {0,0,0,0}, ahn = {0,0,0,0};
#pragma unroll
      for (int kt = 0; kt < 4; ++kt)
        au = MFMA(a[kt], *(const bf16x8*)&G1t[(ct * 16 + lr) * GST + kt * 32 + lg * 8], au, 0, 0, 0);
#pragma unroll
      for (int k2 = 0; k2 < 2; ++k2) {
        bf16x8 amg = a[2 + k2];
        bf16x8 az_ = a[k2];
        int ko = k2 * 32 + lg * 8;
        air = MFMA(amg, *(const bf16x8*)&Wih_l[(      ct * 16 + lr) * WST + ko], air, 0, 0, 0);
        aiz = MFMA(amg, *(const bf16x8*)&Wih_l[( 64 + ct * 16 + lr) * WST + ko], aiz, 0, 0, 0);
        ain = MFMA(amg, *(const bf16x8*)&Wih_l[(128 + ct * 16 + lr) * WST + ko], ain, 0, 0, 0);
        ahr = MFMA(az_, *(const bf16x8*)&Whh_l[(      ct * 16 + lr) * WST + ko], ahr, 0, 0, 0);
        ahz = MFMA(az_, *(const bf16x8*)&Whh_l[( 64 + ct * 16 + lr) * WST + ko], ahz, 0, 0, 0);
        ahn = MFMA(az_, *(const bf16x8*)&Whh_l[(128 + ct * 16 + lr) * WST + ko], ahn, 0, 0, 0);
      }
      int c = ct * 16 + lr;
#pragma unroll
      for (int e = 0; e < 4; ++e) {
        float zv = bf2f(zbf[(long)(rowbase + lg * 4 + e) * 64 + c]);
        zs[ct][e] = zv;
        float uu = fmaxf(au[e] + gb1s[c], 0.0f);
        usum[e] += uu * gw2s[c];
        float rr = sigm(air[e] + bihs[c] + ahr[e] + bhhs[c]);
        float zg = sigm(aiz[e] + bihs[64 + c] + ahz[e] + bhhs[64 + c]);
        float nn = tanhf(ain[e] + bihs[128 + c] + rr * (ahn[e] + bhhs[128 + c]));
        hnew[ct][e] = (1.0f - zg) * nn + zg * zv;
      }
    }

#pragma unroll
    for (int m = 1; m <= 8; m <<= 1)
#pragma unroll
      for (int e = 0; e < 4; ++e) {
        float v = usum[e];
        usum[e] = v + __shfl_xor(v, m, 64);
      }
    float gate[4];
#pragma unroll
    for (int e = 0; e < 4; ++e) gate[e] = sigm(usum[e] + gb2s);

#pragma unroll
    for (int ct = 0; ct < 4; ++ct)
#pragma unroll
      for (int e = 0; e < 4; ++e)
        out[(long)(rowbase + lg * 4 + e) * 64 + ct * 16 + lr] =
            zs[ct][e] + gate[e] * (hnew[ct][e] - zs[ct][e]);
  }
}

extern "C" void kernel_launch(void* const* d_in, const int* in_sizes, int n_in,
                              void* d_out, int out_size, void* d_ws, size_t ws_size,
                              hipStream_t stream) {
  const float* f_pts   = (const float*)d_in[0];
  const float* pts     = (const float*)d_in[1];
  const float* z_lat   = (const float*)d_in[2];
  const float* centers = (const float*)d_in[3];
  const int*   cand    = (const int*)d_in[4];
  const float* sim_w1  = (const float*)d_in[5];
  const float* sim_b1  = (const float*)d_in[6];
  const float* sim_w2  = (const float*)d_in[7];
  // d_in[8] = sim_b2: uniform softmax shift, unused
  const float* gate_w1 = (const float*)d_in[9];
  const float* gate_b1 = (const float*)d_in[10];
  const float* gate_w2 = (const float*)d_in[11];
  const float* gate_b2 = (const float*)d_in[12];
  const float* W_ih    = (const float*)d_in[13];
  const float* W_hh    = (const float*)d_in[14];
  const float* b_ih    = (const float*)d_in[15];
  const float* b_hh    = (const float*)d_in[16];

  int N = in_sizes[0] / 64;
  int M = in_sizes[2] / 64;

  int* cursor = (int*)d_ws;                                        // M i32
  unsigned* rec = (unsigned*)(cursor + M);                         // M*CAP u32
  unsigned short* msg_bf = (unsigned short*)rec;                   // alias: rec consumed by gather
  unsigned short* zbf = (unsigned short*)(rec + (size_t)M * CAP);  // M*64 bf16 (live thru stage2)
  unsigned short* fbf = zbf + (size_t)M * 64;                      // N*64 bf16
  unsigned short* HBt = fbf + (size_t)N * 64;                      // N*64 bf16 (transposed ct-packed)
  short* bfZ = (short*)(HBt + (size_t)N * 64);                     // 12*512 bf16

  prep_kernel<<<2048, 256, 0, stream>>>(z_lat, f_pts, sim_w1, sim_b1,
                                        zbf, fbf, HBt, cursor, bfZ, M);

  int nwaves = (N * 8) / (16 * TPW);                               // 4096 waves
  pair_kernel<<<nwaves / 4, 256, 0, stream>>>(pts, zbf, centers, cand,
                                              sim_w2, bfZ, HBt, cursor, rec);

  gather_kernel<<<(M * 4) / 256, 256, 0, stream>>>(rec, cursor, fbf, msg_bf, M);

  int ntiles = M / 128;
  stage2<<<512, 512, 0, stream>>>(zbf, gate_w1, gate_b1, gate_w2, gate_b2,
                                  W_ih, W_hh, b_ih, b_hh, msg_bf,
                                  (float*)d_out, ntiles);
}

// Round 10
// 163.981 us; speedup vs baseline: 2.0237x; 1.1658x over previous
//
#include <hip/hip_runtime.h>
#include <hip/hip_fp16.h>
#include <math.h>

// LatentVoxelGrid: N=65536 pts, M=131072 voxels, K=8 cand, D=64.
// prep  (z->zbf, cursor=0, pack W1z frags; blocks<1024: HBt=f@W1f+b1 MFMA + fbf)
// pair  (MFMA sim MLP + softmax + bucket records, TPW=8, HBt packed loads)
// gather(per-voxel Sum w*f / Sum w -> normalized bf16 msg; msg aliases rec)
// stage2(gate MLP + GRU, bf16 MFMA; TWO-PASS ct loop to bound live registers)

typedef short bf16x8 __attribute__((ext_vector_type(8)));
typedef unsigned short u16x8 __attribute__((ext_vector_type(8)));
typedef float f32x4 __attribute__((ext_vector_type(4)));
#define MFMA __builtin_amdgcn_mfma_f32_16x16x32_bf16
#define CAP 32

__device__ __forceinline__ short f2bf(float f) {  // round-to-nearest-even
  unsigned u = __float_as_uint(f);
  unsigned r = (u + 0x7FFFu + ((u >> 16) & 1u)) >> 16;
  return (short)r;
}

__device__ __forceinline__ float bf2f(unsigned short h) {
  return __uint_as_float(((unsigned)h) << 16);
}

__device__ __forceinline__ float sigm(float x) { return 1.0f / (1.0f + __expf(-x)); }

// ---- prep: zbf, cursor=0, bfZ pack, HBt + fbf (blocks < 1024) ----
__global__ __launch_bounds__(256) void prep_kernel(
    const float* __restrict__ z, const float* __restrict__ f,
    const float* __restrict__ sim_w1, const float* __restrict__ sim_b1,
    unsigned short* __restrict__ zbf, unsigned short* __restrict__ fbf,
    unsigned short* __restrict__ HBt, int* __restrict__ cursor,
    short* __restrict__ bfZ, int M)
{
  long tid = (long)blockIdx.x * 256 + threadIdx.x;
  long nthr = (long)gridDim.x * 256;

  for (long i = tid; i < M; i += nthr) cursor[i] = 0;

  long nz = (long)M * 64;
  for (long i = tid * 8; i < nz; i += nthr * 8) {
    float4 a = *(const float4*)&z[i];
    float4 b4 = *(const float4*)&z[i + 4];
    u16x8 o;
    o[0] = (unsigned short)f2bf(a.x);  o[1] = (unsigned short)f2bf(a.y);
    o[2] = (unsigned short)f2bf(a.z);  o[3] = (unsigned short)f2bf(a.w);
    o[4] = (unsigned short)f2bf(b4.x); o[5] = (unsigned short)f2bf(b4.y);
    o[6] = (unsigned short)f2bf(b4.z); o[7] = (unsigned short)f2bf(b4.w);
    *(u16x8*)&zbf[i] = o;
  }

  if (blockIdx.x == gridDim.x - 1 && threadIdx.x < 64) {
    int lane = threadIdx.x;
    int lr = lane & 15, lg = lane >> 4;
#pragma unroll
    for (int ct = 0; ct < 4; ++ct)
#pragma unroll
      for (int kt = 0; kt < 3; ++kt) {
        bf16x8 b;
#pragma unroll
        for (int e = 0; e < 8; ++e) {
          int k = kt * 32 + lg * 8 + e;  // 0..95: [z(64) | delta(3) | pad]
          float v = (k < 67) ? sim_w1[(64 + k) * 64 + ct * 16 + lr] : 0.0f;
          b[e] = f2bf(v);
        }
        *(bf16x8*)&bfZ[(ct * 3 + kt) * 512 + lane * 8] = b;
      }
  }

  if (blockIdx.x < 1024) {  // hb: wave handles 16 point-rows; also writes fbf
    int wave = blockIdx.x * 4 + (threadIdx.x >> 6);
    int lane = threadIdx.x & 63;
    int lr = lane & 15, lg = lane >> 4;
    int n0 = wave * 16;

    bf16x8 bf[8];  // f-part B frags (sim_w1 is L2-hot)
#pragma unroll
    for (int ct = 0; ct < 4; ++ct)
#pragma unroll
      for (int kt = 0; kt < 2; ++kt) {
        bf16x8 bb;
#pragma unroll
        for (int e = 0; e < 8; ++e)
          bb[e] = f2bf(sim_w1[(kt * 32 + lg * 8 + e) * 64 + ct * 16 + lr]);
        bf[ct * 2 + kt] = bb;
      }

    bf16x8 a[2];
#pragma unroll
    for (int kt = 0; kt < 2; ++kt) {
      const float* src = &f[(long)(n0 + lr) * 64 + kt * 32 + lg * 8];
      float4 v0 = *(const float4*)src;
      float4 v1 = *(const float4*)(src + 4);
      bf16x8 t;
      t[0] = f2bf(v0.x); t[1] = f2bf(v0.y); t[2] = f2bf(v0.z); t[3] = f2bf(v0.w);
      t[4] = f2bf(v1.x); t[5] = f2bf(v1.y); t[6] = f2bf(v1.z); t[7] = f2bf(v1.w);
      a[kt] = t;
    }
    *(bf16x8*)&fbf[(long)(n0 + lr) * 64 + lg * 8] = a[0];
    *(bf16x8*)&fbf[(long)(n0 + lr) * 64 + 32 + lg * 8] = a[1];

    f32x4 acc[4] = {{0,0,0,0},{0,0,0,0},{0,0,0,0},{0,0,0,0}};
#pragma unroll
    for (int ct = 0; ct < 4; ++ct) {
      acc[ct] = MFMA(a[0], bf[ct * 2 + 0], acc[ct], 0, 0, 0);
      acc[ct] = MFMA(a[1], bf[ct * 2 + 1], acc[ct], 0, 0, 0);
    }
    float b10 = sim_b1[lr], b11 = sim_b1[16 + lr];
    float b12 = sim_b1[32 + lr], b13 = sim_b1[48 + lr];
#pragma unroll
    for (int e = 0; e < 4; ++e) {
      // HBt packed: [n][lr*4 + ct] so pair reads hb[0..3] as one 8B load
      unsigned lo = (unsigned)(unsigned short)f2bf(acc[0][e] + b10)
                  | ((unsigned)(unsigned short)f2bf(acc[1][e] + b11) << 16);
      unsigned hi = (unsigned)(unsigned short)f2bf(acc[2][e] + b12)
                  | ((unsigned)(unsigned short)f2bf(acc[3][e] + b13) << 16);
      *(uint2*)&HBt[(long)(n0 + lg * 4 + e) * 64 + lr * 4] = make_uint2(lo, hi);
    }
  }
}

// ---- pair: sim MLP + softmax; TPW=8, 2 records per lane ----
#define TPW 8
__global__ __launch_bounds__(256) void pair_kernel(
    const float* __restrict__ pts, const unsigned short* __restrict__ zbf,
    const float* __restrict__ centers, const int* __restrict__ cand_idx,
    const float* __restrict__ sim_w2, const short* __restrict__ bfZ,
    const unsigned short* __restrict__ HBt,
    int* __restrict__ cursor, unsigned* __restrict__ rec)
{
  int wave = (blockIdx.x * 256 + threadIdx.x) >> 6;
  int lane = threadIdx.x & 63;
  int lr = lane & 15, lg = lane >> 4;

  // this wave owns pairs wave*128..+128; lane owns records lane and 64+lane
  int callA = cand_idx[wave * 128 + lane];
  int callB = cand_idx[wave * 128 + 64 + lane];
  int slotA = atomicAdd(&cursor[callA], 1);  // early; hidden under compute
  int slotB = atomicAdd(&cursor[callB], 1);

  bf16x8 b[12];
#pragma unroll
  for (int i = 0; i < 12; ++i) b[i] = *(const bf16x8*)&bfZ[i * 512 + lane * 8];
  float w2c[4];
#pragma unroll
  for (int ct = 0; ct < 4; ++ct) w2c[ct] = sim_w2[ct * 16 + lr];

  // prologue: tile 0 operand loads
  int c0 = __shfl(callA, lr, 64);
  bf16x8 a0 = *(const bf16x8*)&zbf[(long)c0 * 64 + lg * 8];
  bf16x8 a1 = *(const bf16x8*)&zbf[(long)c0 * 64 + 32 + lg * 8];
  float cx = 0, cy = 0, cz = 0, px = 0, py = 0, pz = 0;
  if (lg == 0) {
    cx = centers[c0 * 3 + 0]; cy = centers[c0 * 3 + 1]; cz = centers[c0 * 3 + 2];
    int n = wave * TPW * 2 + (lr >> 3);
    px = pts[n * 3 + 0]; py = pts[n * 3 + 1]; pz = pts[n * 3 + 2];
  }
  uint2 h2 = *(const uint2*)&HBt[((long)wave * TPW * 2 + (lg >> 1)) * 64 + lr * 4];

  float wst[TPW];  // per-tile stashed weight (valid on lanes 0..15)

#pragma unroll
  for (int t = 0; t < TPW; ++t) {
    // prefetch tile t+1 while computing tile t
    int cn = c0; bf16x8 an0 = a0, an1 = a1;
    float cxn = 0, cyn = 0, czn = 0, pxn = 0, pyn = 0, pzn = 0;
    uint2 h2n = make_uint2(0, 0);
    if (t + 1 < TPW) {
      cn = __shfl((t + 1) < 4 ? callA : callB, ((t + 1) & 3) * 16 + lr, 64);
      an0 = *(const bf16x8*)&zbf[(long)cn * 64 + lg * 8];
      an1 = *(const bf16x8*)&zbf[(long)cn * 64 + 32 + lg * 8];
      if (lg == 0) {
        cxn = centers[cn * 3 + 0]; cyn = centers[cn * 3 + 1]; czn = centers[cn * 3 + 2];
        int n = (wave * TPW + t + 1) * 2 + (lr >> 3);
        pxn = pts[n * 3 + 0]; pyn = pts[n * 3 + 1]; pzn = pts[n * 3 + 2];
      }
      h2n = *(const uint2*)&HBt[((long)(wave * TPW + t + 1) * 2 + (lg >> 1)) * 64 + lr * 4];
    }

    bf16x8 ad = {0, 0, 0, 0, 0, 0, 0, 0};
    if (lg == 0) {
      ad[0] = f2bf(px - cx); ad[1] = f2bf(py - cy); ad[2] = f2bf(pz - cz);
    }

    f32x4 acc[4] = {{0,0,0,0},{0,0,0,0},{0,0,0,0},{0,0,0,0}};
#pragma unroll
    for (int ct = 0; ct < 4; ++ct) {
      acc[ct] = MFMA(a0, b[ct * 3 + 0], acc[ct], 0, 0, 0);
      acc[ct] = MFMA(a1, b[ct * 3 + 1], acc[ct], 0, 0, 0);
      acc[ct] = MFMA(ad, b[ct * 3 + 2], acc[ct], 0, 0, 0);
    }

    float hb[4];
    hb[0] = bf2f((unsigned short)(h2.x));
    hb[1] = bf2f((unsigned short)(h2.x >> 16));
    hb[2] = bf2f((unsigned short)(h2.y));
    hb[3] = bf2f((unsigned short)(h2.y >> 16));

    f32x4 part = {0.f, 0.f, 0.f, 0.f};
#pragma unroll
    for (int ct = 0; ct < 4; ++ct)
#pragma unroll
      for (int e = 0; e < 4; ++e) {
        float u = fmaxf(acc[ct][e] + hb[ct], 0.0f);
        part[e] = fmaf(u, w2c[ct], part[e]);
      }
#pragma unroll
    for (int m = 1; m <= 8; m <<= 1)
#pragma unroll
      for (int e = 0; e < 4; ++e) part[e] += __shfl_xor(part[e], m, 64);

    float other[4];
#pragma unroll
    for (int e = 0; e < 4; ++e) other[e] = __shfl_xor(part[e], 16, 64);

    float mx = part[0];
#pragma unroll
    for (int e = 1; e < 4; ++e) mx = fmaxf(mx, part[e]);
#pragma unroll
    for (int e = 0; e < 4; ++e) mx = fmaxf(mx, other[e]);
    float ex[4], se = 0.f, so = 0.f;
#pragma unroll
    for (int e = 0; e < 4; ++e) {
      ex[e] = __expf((part[e] - mx) * (1.0f / 0.3f));
      se += ex[e];
      so += __expf((other[e] - mx) * (1.0f / 0.3f));
    }
    float inv = 1.0f / (se + so);

    // wst[t] lane r (0..15): weight of MFMA row r (= w[r&3] from lane (r>>2)*16)
    int srcl = (lane >> 2) << 4;
    float t0 = __shfl(ex[0] * inv, srcl, 64);
    float t1 = __shfl(ex[1] * inv, srcl, 64);
    float t2 = __shfl(ex[2] * inv, srcl, 64);
    float t3 = __shfl(ex[3] * inv, srcl, 64);
    int esel = lane & 3;
    wst[t] = esel == 0 ? t0 : esel == 1 ? t1 : esel == 2 ? t2 : t3;

    c0 = cn; a0 = an0; a1 = an1;
    cx = cxn; cy = cyn; cz = czn; px = pxn; py = pyn; pz = pzn;
    h2 = h2n;
  }

  // epilogue: route tile t's row-lr weight to the owning lane
  float v0 = __shfl(wst[0], lr, 64);
  float v1 = __shfl(wst[1], lr, 64);
  float v2 = __shfl(wst[2], lr, 64);
  float v3 = __shfl(wst[3], lr, 64);
  float v4 = __shfl(wst[4], lr, 64);
  float v5 = __shfl(wst[5], lr, 64);
  float v6 = __shfl(wst[6], lr, 64);
  float v7 = __shfl(wst[7], lr, 64);
  float wvA = lg == 0 ? v0 : lg == 1 ? v1 : lg == 2 ? v2 : v3;
  float wvB = lg == 0 ? v4 : lg == 1 ? v5 : lg == 2 ? v6 : v7;

  int base_pt = wave * 16 + 2 * lg + (lr >> 3);
  if (slotA < CAP) {
    unsigned short wh = __half_as_ushort(__float2half(wvA));
    rec[(long)callA * CAP + slotA] = ((unsigned)base_pt << 16) | (unsigned)wh;
  }
  if (slotB < CAP) {
    unsigned short wh = __half_as_ushort(__float2half(wvB));
    rec[(long)callB * CAP + slotB] = ((unsigned)(base_pt + 8) << 16) | (unsigned)wh;
  }
}

// ---- gather: msg[v] = (Sum w*f[n]) / (Sum w + eps); msg ALIASES rec rows ----
__global__ __launch_bounds__(256) void gather_kernel(
    const unsigned* __restrict__ rec, const int* __restrict__ cursor,
    const unsigned short* __restrict__ fbf, unsigned short* __restrict__ msg_bf,
    int mvox)
{
  int tid = blockIdx.x * 256 + threadIdx.x;
  int row = tid >> 2, seg = tid & 3;  // 4 threads per voxel, 16 cols each
  if (row >= mvox) return;

  int cnt = cursor[row];
  cnt = cnt < CAP ? cnt : CAP;
  const unsigned* rp = &rec[(long)row * CAP];

  float acc[16];
#pragma unroll
  for (int j = 0; j < 16; ++j) acc[j] = 0.f;
  float ws = 0.f;

  for (int i0 = 0; i0 < cnt; i0 += 4) {   // rec row chunked 4-wide: fbf loads overlap
    uint4 r4 = *(const uint4*)&rp[i0];
    unsigned rr0 = r4.x, rr1 = r4.y, rr2 = r4.z, rr3 = r4.w;
#pragma unroll
    for (int j = 0; j < 4; ++j) {
      unsigned r = j == 0 ? rr0 : j == 1 ? rr1 : j == 2 ? rr2 : rr3;
      if (i0 + j < cnt) {
        float w = __half2float(__ushort_as_half((unsigned short)(r & 0xffffu)));
        int n = r >> 16;
        ws += w;
        const u16x8* fp = (const u16x8*)&fbf[(long)n * 64 + seg * 16];
        u16x8 f0 = fp[0], f1 = fp[1];
#pragma unroll
        for (int k = 0; k < 8; ++k) {
          acc[k]     = fmaf(w, bf2f(f0[k]), acc[k]);
          acc[8 + k] = fmaf(w, bf2f(f1[k]), acc[8 + k]);
        }
      }
    }
  }
  float inv = 1.0f / (ws + 1e-6f);
  u16x8 o0, o1;
#pragma unroll
  for (int j = 0; j < 8; ++j) {
    o0[j] = (unsigned short)f2bf(acc[j] * inv);
    o1[j] = (unsigned short)f2bf(acc[8 + j] * inv);
  }
  // writes land in this voxel's own (already consumed) rec row
  *(u16x8*)&msg_bf[(long)row * 64 + seg * 16] = o0;
  *(u16x8*)&msg_bf[(long)row * 64 + seg * 16 + 8] = o1;
}

// ---- Stage 2: gate MLP + GRU; TWO-PASS ct loop (bounded live registers) ----
#define GST 136
#define WST 72

__global__ __launch_bounds__(512) void stage2(
    const unsigned short* __restrict__ zbf,
    const float* __restrict__ gate_w1, const float* __restrict__ gate_b1,
    const float* __restrict__ gate_w2, const float* __restrict__ gate_b2,
    const float* __restrict__ W_ih, const float* __restrict__ W_hh,
    const float* __restrict__ b_ih, const float* __restrict__ b_hh,
    const unsigned short* __restrict__ msg_bf,
    float* __restrict__ out, int ntiles)
{
  __shared__ short G1t[64 * GST];
  __shared__ short Wih_l[192 * WST];
  __shared__ short Whh_l[192 * WST];
  __shared__ float gb1s[64], gw2s[64], bihs[192], bhhs[192];
  __shared__ float gb2s;

  int t = threadIdx.x;
  for (int s = t; s < 64 * 128; s += 512) {
    int j = s & 63, k = s >> 6;
    G1t[j * GST + k] = f2bf(gate_w1[s]);
  }
  for (int s = t; s < 192 * 64; s += 512) {
    int j = s >> 6, k = s & 63;
    Wih_l[j * WST + k] = f2bf(W_ih[s]);
    Whh_l[j * WST + k] = f2bf(W_hh[s]);
  }
  if (t < 64) { gb1s[t] = gate_b1[t]; gw2s[t] = gate_w2[t]; }
  if (t < 192) { bihs[t] = b_ih[t]; bhhs[t] = b_hh[t]; }
  if (t == 0) gb2s = gate_b2[0];
  __syncthreads();

  int wid = t >> 6, lane = t & 63;
  int lr = lane & 15, lg = lane >> 4;

#pragma unroll 1
  for (int tile = blockIdx.x; tile < ntiles; tile += gridDim.x) {
    int rowbase = tile * 128 + wid * 16;
    long abase = (long)(rowbase + lr) * 64;
    bf16x8 a0 = *(const bf16x8*)&zbf[abase + lg * 8];
    bf16x8 a1 = *(const bf16x8*)&zbf[abase + 32 + lg * 8];
    bf16x8 a2 = *(const bf16x8*)&msg_bf[abase + lg * 8];
    bf16x8 a3 = *(const bf16x8*)&msg_bf[abase + 32 + lg * 8];

    // ---- pass 1: gate (only au live per ct) ----
    f32x4 usum = {0.f, 0.f, 0.f, 0.f};
#pragma unroll
    for (int ct = 0; ct < 4; ++ct) {
      f32x4 au = {0, 0, 0, 0};
      au = MFMA(a0, *(const bf16x8*)&G1t[(ct * 16 + lr) * GST +  0 + lg * 8], au, 0, 0, 0);
      au = MFMA(a1, *(const bf16x8*)&G1t[(ct * 16 + lr) * GST + 32 + lg * 8], au, 0, 0, 0);
      au = MFMA(a2, *(const bf16x8*)&G1t[(ct * 16 + lr) * GST + 64 + lg * 8], au, 0, 0, 0);
      au = MFMA(a3, *(const bf16x8*)&G1t[(ct * 16 + lr) * GST + 96 + lg * 8], au, 0, 0, 0);
      int c = ct * 16 + lr;
#pragma unroll
      for (int e = 0; e < 4; ++e)
        usum[e] += fmaxf(au[e] + gb1s[c], 0.0f) * gw2s[c];
    }
#pragma unroll
    for (int m = 1; m <= 8; m <<= 1)
#pragma unroll
      for (int e = 0; e < 4; ++e) {
        float v = usum[e];
        usum[e] = v + __shfl_xor(v, m, 64);
      }
    float gate[4];
#pragma unroll
    for (int e = 0; e < 4; ++e) gate[e] = sigm(usum[e] + gb2s);

    // ---- pass 2: GRU, write out immediately per ct ----
#pragma unroll
    for (int ct = 0; ct < 4; ++ct) {
      f32x4 air = {0,0,0,0}, aiz = {0,0,0,0}, ain = {0,0,0,0};
      f32x4 ahr = {0,0,0,0}, ahz = {0,0,0,0}, ahn = {0,0,0,0};
#pragma unroll
      for (int k2 = 0; k2 < 2; ++k2) {
        bf16x8 amg = k2 ? a3 : a2;
        bf16x8 az_ = k2 ? a1 : a0;
        int ko = k2 * 32 + lg * 8;
        air = MFMA(amg, *(const bf16x8*)&Wih_l[(      ct * 16 + lr) * WST + ko], air, 0, 0, 0);
        aiz = MFMA(amg, *(const bf16x8*)&Wih_l[( 64 + ct * 16 + lr) * WST + ko], aiz, 0, 0, 0);
        ain = MFMA(amg, *(const bf16x8*)&Wih_l[(128 + ct * 16 + lr) * WST + ko], ain, 0, 0, 0);
        ahr = MFMA(az_, *(const bf16x8*)&Whh_l[(      ct * 16 + lr) * WST + ko], ahr, 0, 0, 0);
        ahz = MFMA(az_, *(const bf16x8*)&Whh_l[( 64 + ct * 16 + lr) * WST + ko], ahz, 0, 0, 0);
        ahn = MFMA(az_, *(const bf16x8*)&Whh_l[(128 + ct * 16 + lr) * WST + ko], ahn, 0, 0, 0);
      }
      int c = ct * 16 + lr;
#pragma unroll
      for (int e = 0; e < 4; ++e) {
        float zv = bf2f(zbf[(long)(rowbase + lg * 4 + e) * 64 + c]);
        float rr = sigm(air[e] + bihs[c] + ahr[e] + bhhs[c]);
        float zg = sigm(aiz[e] + bihs[64 + c] + ahz[e] + bhhs[64 + c]);
        float nn = tanhf(ain[e] + bihs[128 + c] + rr * (ahn[e] + bhhs[128 + c]));
        float hnew = (1.0f - zg) * nn + zg * zv;
        out[(long)(rowbase + lg * 4 + e) * 64 + c] = zv + gate[e] * (hnew - zv);
      }
    }
  }
}

extern "C" void kernel_launch(void* const* d_in, const int* in_sizes, int n_in,
                              void* d_out, int out_size, void* d_ws, size_t ws_size,
                              hipStream_t stream) {
  const float* f_pts   = (const float*)d_in[0];
  const float* pts     = (const float*)d_in[1];
  const float* z_lat   = (const float*)d_in[2];
  const float* centers = (const float*)d_in[3];
  const int*   cand    = (const int*)d_in[4];
  const float* sim_w1  = (const float*)d_in[5];
  const float* sim_b1  = (const float*)d_in[6];
  const float* sim_w2  = (const float*)d_in[7];
  // d_in[8] = sim_b2: uniform softmax shift, unused
  const float* gate_w1 = (const float*)d_in[9];
  const float* gate_b1 = (const float*)d_in[10];
  const float* gate_w2 = (const float*)d_in[11];
  const float* gate_b2 = (const float*)d_in[12];
  const float* W_ih    = (const float*)d_in[13];
  const float* W_hh    = (const float*)d_in[14];
  const float* b_ih    = (const float*)d_in[15];
  const float* b_hh    = (const float*)d_in[16];

  int N = in_sizes[0] / 64;
  int M = in_sizes[2] / 64;

  int* cursor = (int*)d_ws;                                        // M i32
  unsigned* rec = (unsigned*)(cursor + M);                         // M*CAP u32
  unsigned short* msg_bf = (unsigned short*)rec;                   // alias: rec consumed by gather
  unsigned short* zbf = (unsigned short*)(rec + (size_t)M * CAP);  // M*64 bf16 (live thru stage2)
  unsigned short* fbf = zbf + (size_t)M * 64;                      // N*64 bf16
  unsigned short* HBt = fbf + (size_t)N * 64;                      // N*64 bf16 (transposed ct-packed)
  short* bfZ = (short*)(HBt + (size_t)N * 64);                     // 12*512 bf16

  prep_kernel<<<2048, 256, 0, stream>>>(z_lat, f_pts, sim_w1, sim_b1,
                                        zbf, fbf, HBt, cursor, bfZ, M);

  int nwaves = (N * 8) / (16 * TPW);                               // 4096 waves
  pair_kernel<<<nwaves / 4, 256, 0, stream>>>(pts, zbf, centers, cand,
                                              sim_w2, bfZ, HBt, cursor, rec);

  gather_kernel<<<(M * 4) / 256, 256, 0, stream>>>(rec, cursor, fbf, msg_bf, M);

  int ntiles = M / 128;
  stage2<<<512, 512, 0, stream>>>(zbf, gate_w1, gate_b1, gate_w2, gate_b2,
                                  W_ih, W_hh, b_ih, b_hh, msg_bf,
                                  (float*)d_out, ntiles);
}

// Round 11
// 113.737 us; speedup vs baseline: 2.9177x; 1.4418x over previous
//
#include <hip/hip_runtime.h>
#include <hip/hip_fp16.h>
#include <math.h>

// LatentVoxelGrid: N=65536 pts, M=131072 voxels, K=8 cand, D=64.
// prep  (z->zbf, cursor=0, pack W1z frags; blocks<1024: HBt=f@W1f+b1 MFMA + fbf)
// pair  (MFMA sim MLP + softmax + bucket records, TPW=8, HBt packed loads)
// gather(per-voxel Sum w*f / Sum w -> normalized bf16 msg; msg aliases rec)
// stage2(gate MLP + GRU, bf16 MFMA; two-pass ct loop, waves_per_eu(2,2) to
//        un-cap VGPR at 256 — LDS-derived 4-wave target was forcing spills)

typedef short bf16x8 __attribute__((ext_vector_type(8)));
typedef unsigned short u16x8 __attribute__((ext_vector_type(8)));
typedef float f32x4 __attribute__((ext_vector_type(4)));
#define MFMA __builtin_amdgcn_mfma_f32_16x16x32_bf16
#define CAP 32

__device__ __forceinline__ short f2bf(float f) {  // round-to-nearest-even
  unsigned u = __float_as_uint(f);
  unsigned r = (u + 0x7FFFu + ((u >> 16) & 1u)) >> 16;
  return (short)r;
}

__device__ __forceinline__ float bf2f(unsigned short h) {
  return __uint_as_float(((unsigned)h) << 16);
}

__device__ __forceinline__ float sigm(float x) { return 1.0f / (1.0f + __expf(-x)); }

// ---- prep: zbf, cursor=0, bfZ pack, HBt + fbf (blocks < 1024) ----
__global__ __launch_bounds__(256) void prep_kernel(
    const float* __restrict__ z, const float* __restrict__ f,
    const float* __restrict__ sim_w1, const float* __restrict__ sim_b1,
    unsigned short* __restrict__ zbf, unsigned short* __restrict__ fbf,
    unsigned short* __restrict__ HBt, int* __restrict__ cursor,
    short* __restrict__ bfZ, int M)
{
  long tid = (long)blockIdx.x * 256 + threadIdx.x;
  long nthr = (long)gridDim.x * 256;

  for (long i = tid; i < M; i += nthr) cursor[i] = 0;

  long nz = (long)M * 64;
  for (long i = tid * 8; i < nz; i += nthr * 8) {
    float4 a = *(const float4*)&z[i];
    float4 b4 = *(const float4*)&z[i + 4];
    u16x8 o;
    o[0] = (unsigned short)f2bf(a.x);  o[1] = (unsigned short)f2bf(a.y);
    o[2] = (unsigned short)f2bf(a.z);  o[3] = (unsigned short)f2bf(a.w);
    o[4] = (unsigned short)f2bf(b4.x); o[5] = (unsigned short)f2bf(b4.y);
    o[6] = (unsigned short)f2bf(b4.z); o[7] = (unsigned short)f2bf(b4.w);
    *(u16x8*)&zbf[i] = o;
  }

  if (blockIdx.x == gridDim.x - 1 && threadIdx.x < 64) {
    int lane = threadIdx.x;
    int lr = lane & 15, lg = lane >> 4;
#pragma unroll
    for (int ct = 0; ct < 4; ++ct)
#pragma unroll
      for (int kt = 0; kt < 3; ++kt) {
        bf16x8 b;
#pragma unroll
        for (int e = 0; e < 8; ++e) {
          int k = kt * 32 + lg * 8 + e;  // 0..95: [z(64) | delta(3) | pad]
          float v = (k < 67) ? sim_w1[(64 + k) * 64 + ct * 16 + lr] : 0.0f;
          b[e] = f2bf(v);
        }
        *(bf16x8*)&bfZ[(ct * 3 + kt) * 512 + lane * 8] = b;
      }
  }

  if (blockIdx.x < 1024) {  // hb: wave handles 16 point-rows; also writes fbf
    int wave = blockIdx.x * 4 + (threadIdx.x >> 6);
    int lane = threadIdx.x & 63;
    int lr = lane & 15, lg = lane >> 4;
    int n0 = wave * 16;

    bf16x8 bf[8];  // f-part B frags (sim_w1 is L2-hot)
#pragma unroll
    for (int ct = 0; ct < 4; ++ct)
#pragma unroll
      for (int kt = 0; kt < 2; ++kt) {
        bf16x8 bb;
#pragma unroll
        for (int e = 0; e < 8; ++e)
          bb[e] = f2bf(sim_w1[(kt * 32 + lg * 8 + e) * 64 + ct * 16 + lr]);
        bf[ct * 2 + kt] = bb;
      }

    bf16x8 a[2];
#pragma unroll
    for (int kt = 0; kt < 2; ++kt) {
      const float* src = &f[(long)(n0 + lr) * 64 + kt * 32 + lg * 8];
      float4 v0 = *(const float4*)src;
      float4 v1 = *(const float4*)(src + 4);
      bf16x8 t;
      t[0] = f2bf(v0.x); t[1] = f2bf(v0.y); t[2] = f2bf(v0.z); t[3] = f2bf(v0.w);
      t[4] = f2bf(v1.x); t[5] = f2bf(v1.y); t[6] = f2bf(v1.z); t[7] = f2bf(v1.w);
      a[kt] = t;
    }
    *(bf16x8*)&fbf[(long)(n0 + lr) * 64 + lg * 8] = a[0];
    *(bf16x8*)&fbf[(long)(n0 + lr) * 64 + 32 + lg * 8] = a[1];

    f32x4 acc[4] = {{0,0,0,0},{0,0,0,0},{0,0,0,0},{0,0,0,0}};
#pragma unroll
    for (int ct = 0; ct < 4; ++ct) {
      acc[ct] = MFMA(a[0], bf[ct * 2 + 0], acc[ct], 0, 0, 0);
      acc[ct] = MFMA(a[1], bf[ct * 2 + 1], acc[ct], 0, 0, 0);
    }
    float b10 = sim_b1[lr], b11 = sim_b1[16 + lr];
    float b12 = sim_b1[32 + lr], b13 = sim_b1[48 + lr];
#pragma unroll
    for (int e = 0; e < 4; ++e) {
      // HBt packed: [n][lr*4 + ct] so pair reads hb[0..3] as one 8B load
      unsigned lo = (unsigned)(unsigned short)f2bf(acc[0][e] + b10)
                  | ((unsigned)(unsigned short)f2bf(acc[1][e] + b11) << 16);
      unsigned hi = (unsigned)(unsigned short)f2bf(acc[2][e] + b12)
                  | ((unsigned)(unsigned short)f2bf(acc[3][e] + b13) << 16);
      *(uint2*)&HBt[(long)(n0 + lg * 4 + e) * 64 + lr * 4] = make_uint2(lo, hi);
    }
  }
}

// ---- pair: sim MLP + softmax; TPW=8, 2 records per lane ----
#define TPW 8
__global__ __launch_bounds__(256) void pair_kernel(
    const float* __restrict__ pts, const unsigned short* __restrict__ zbf,
    const float* __restrict__ centers, const int* __restrict__ cand_idx,
    const float* __restrict__ sim_w2, const short* __restrict__ bfZ,
    const unsigned short* __restrict__ HBt,
    int* __restrict__ cursor, unsigned* __restrict__ rec)
{
  int wave = (blockIdx.x * 256 + threadIdx.x) >> 6;
  int lane = threadIdx.x & 63;
  int lr = lane & 15, lg = lane >> 4;

  // this wave owns pairs wave*128..+128; lane owns records lane and 64+lane
  int callA = cand_idx[wave * 128 + lane];
  int callB = cand_idx[wave * 128 + 64 + lane];
  int slotA = atomicAdd(&cursor[callA], 1);  // early; hidden under compute
  int slotB = atomicAdd(&cursor[callB], 1);

  bf16x8 b[12];
#pragma unroll
  for (int i = 0; i < 12; ++i) b[i] = *(const bf16x8*)&bfZ[i * 512 + lane * 8];
  float w2c[4];
#pragma unroll
  for (int ct = 0; ct < 4; ++ct) w2c[ct] = sim_w2[ct * 16 + lr];

  // prologue: tile 0 operand loads
  int c0 = __shfl(callA, lr, 64);
  bf16x8 a0 = *(const bf16x8*)&zbf[(long)c0 * 64 + lg * 8];
  bf16x8 a1 = *(const bf16x8*)&zbf[(long)c0 * 64 + 32 + lg * 8];
  float cx = 0, cy = 0, cz = 0, px = 0, py = 0, pz = 0;
  if (lg == 0) {
    cx = centers[c0 * 3 + 0]; cy = centers[c0 * 3 + 1]; cz = centers[c0 * 3 + 2];
    int n = wave * TPW * 2 + (lr >> 3);
    px = pts[n * 3 + 0]; py = pts[n * 3 + 1]; pz = pts[n * 3 + 2];
  }
  uint2 h2 = *(const uint2*)&HBt[((long)wave * TPW * 2 + (lg >> 1)) * 64 + lr * 4];

  float wst[TPW];  // per-tile stashed weight (valid on lanes 0..15)

#pragma unroll
  for (int t = 0; t < TPW; ++t) {
    // prefetch tile t+1 while computing tile t
    int cn = c0; bf16x8 an0 = a0, an1 = a1;
    float cxn = 0, cyn = 0, czn = 0, pxn = 0, pyn = 0, pzn = 0;
    uint2 h2n = make_uint2(0, 0);
    if (t + 1 < TPW) {
      cn = __shfl((t + 1) < 4 ? callA : callB, ((t + 1) & 3) * 16 + lr, 64);
      an0 = *(const bf16x8*)&zbf[(long)cn * 64 + lg * 8];
      an1 = *(const bf16x8*)&zbf[(long)cn * 64 + 32 + lg * 8];
      if (lg == 0) {
        cxn = centers[cn * 3 + 0]; cyn = centers[cn * 3 + 1]; czn = centers[cn * 3 + 2];
        int n = (wave * TPW + t + 1) * 2 + (lr >> 3);
        pxn = pts[n * 3 + 0]; pyn = pts[n * 3 + 1]; pzn = pts[n * 3 + 2];
      }
      h2n = *(const uint2*)&HBt[((long)(wave * TPW + t + 1) * 2 + (lg >> 1)) * 64 + lr * 4];
    }

    bf16x8 ad = {0, 0, 0, 0, 0, 0, 0, 0};
    if (lg == 0) {
      ad[0] = f2bf(px - cx); ad[1] = f2bf(py - cy); ad[2] = f2bf(pz - cz);
    }

    f32x4 acc[4] = {{0,0,0,0},{0,0,0,0},{0,0,0,0},{0,0,0,0}};
#pragma unroll
    for (int ct = 0; ct < 4; ++ct) {
      acc[ct] = MFMA(a0, b[ct * 3 + 0], acc[ct], 0, 0, 0);
      acc[ct] = MFMA(a1, b[ct * 3 + 1], acc[ct], 0, 0, 0);
      acc[ct] = MFMA(ad, b[ct * 3 + 2], acc[ct], 0, 0, 0);
    }

    float hb[4];
    hb[0] = bf2f((unsigned short)(h2.x));
    hb[1] = bf2f((unsigned short)(h2.x >> 16));
    hb[2] = bf2f((unsigned short)(h2.y));
    hb[3] = bf2f((unsigned short)(h2.y >> 16));

    f32x4 part = {0.f, 0.f, 0.f, 0.f};
#pragma unroll
    for (int ct = 0; ct < 4; ++ct)
#pragma unroll
      for (int e = 0; e < 4; ++e) {
        float u = fmaxf(acc[ct][e] + hb[ct], 0.0f);
        part[e] = fmaf(u, w2c[ct], part[e]);
      }
#pragma unroll
    for (int m = 1; m <= 8; m <<= 1)
#pragma unroll
      for (int e = 0; e < 4; ++e) part[e] += __shfl_xor(part[e], m, 64);

    float other[4];
#pragma unroll
    for (int e = 0; e < 4; ++e) other[e] = __shfl_xor(part[e], 16, 64);

    float mx = part[0];
#pragma unroll
    for (int e = 1; e < 4; ++e) mx = fmaxf(mx, part[e]);
#pragma unroll
    for (int e = 0; e < 4; ++e) mx = fmaxf(mx, other[e]);
    float ex[4], se = 0.f, so = 0.f;
#pragma unroll
    for (int e = 0; e < 4; ++e) {
      ex[e] = __expf((part[e] - mx) * (1.0f / 0.3f));
      se += ex[e];
      so += __expf((other[e] - mx) * (1.0f / 0.3f));
    }
    float inv = 1.0f / (se + so);

    // wst[t] lane r (0..15): weight of MFMA row r (= w[r&3] from lane (r>>2)*16)
    int srcl = (lane >> 2) << 4;
    float t0 = __shfl(ex[0] * inv, srcl, 64);
    float t1 = __shfl(ex[1] * inv, srcl, 64);
    float t2 = __shfl(ex[2] * inv, srcl, 64);
    float t3 = __shfl(ex[3] * inv, srcl, 64);
    int esel = lane & 3;
    wst[t] = esel == 0 ? t0 : esel == 1 ? t1 : esel == 2 ? t2 : t3;

    c0 = cn; a0 = an0; a1 = an1;
    cx = cxn; cy = cyn; cz = czn; px = pxn; py = pyn; pz = pzn;
    h2 = h2n;
  }

  // epilogue: route tile t's row-lr weight to the owning lane
  float v0 = __shfl(wst[0], lr, 64);
  float v1 = __shfl(wst[1], lr, 64);
  float v2 = __shfl(wst[2], lr, 64);
  float v3 = __shfl(wst[3], lr, 64);
  float v4 = __shfl(wst[4], lr, 64);
  float v5 = __shfl(wst[5], lr, 64);
  float v6 = __shfl(wst[6], lr, 64);
  float v7 = __shfl(wst[7], lr, 64);
  float wvA = lg == 0 ? v0 : lg == 1 ? v1 : lg == 2 ? v2 : v3;
  float wvB = lg == 0 ? v4 : lg == 1 ? v5 : lg == 2 ? v6 : v7;

  int base_pt = wave * 16 + 2 * lg + (lr >> 3);
  if (slotA < CAP) {
    unsigned short wh = __half_as_ushort(__float2half(wvA));
    rec[(long)callA * CAP + slotA] = ((unsigned)base_pt << 16) | (unsigned)wh;
  }
  if (slotB < CAP) {
    unsigned short wh = __half_as_ushort(__float2half(wvB));
    rec[(long)callB * CAP + slotB] = ((unsigned)(base_pt + 8) << 16) | (unsigned)wh;
  }
}

// ---- gather: msg[v] = (Sum w*f[n]) / (Sum w + eps); msg ALIASES rec rows ----
__global__ __launch_bounds__(256) void gather_kernel(
    const unsigned* __restrict__ rec, const int* __restrict__ cursor,
    const unsigned short* __restrict__ fbf, unsigned short* __restrict__ msg_bf,
    int mvox)
{
  int tid = blockIdx.x * 256 + threadIdx.x;
  int row = tid >> 2, seg = tid & 3;  // 4 threads per voxel, 16 cols each
  if (row >= mvox) return;

  int cnt = cursor[row];
  cnt = cnt < CAP ? cnt : CAP;
  const unsigned* rp = &rec[(long)row * CAP];

  float acc[16];
#pragma unroll
  for (int j = 0; j < 16; ++j) acc[j] = 0.f;
  float ws = 0.f;

  for (int i0 = 0; i0 < cnt; i0 += 4) {   // rec row chunked 4-wide: fbf loads overlap
    uint4 r4 = *(const uint4*)&rp[i0];
    unsigned rr0 = r4.x, rr1 = r4.y, rr2 = r4.z, rr3 = r4.w;
#pragma unroll
    for (int j = 0; j < 4; ++j) {
      unsigned r = j == 0 ? rr0 : j == 1 ? rr1 : j == 2 ? rr2 : rr3;
      if (i0 + j < cnt) {
        float w = __half2float(__ushort_as_half((unsigned short)(r & 0xffffu)));
        int n = r >> 16;
        ws += w;
        const u16x8* fp = (const u16x8*)&fbf[(long)n * 64 + seg * 16];
        u16x8 f0 = fp[0], f1 = fp[1];
#pragma unroll
        for (int k = 0; k < 8; ++k) {
          acc[k]     = fmaf(w, bf2f(f0[k]), acc[k]);
          acc[8 + k] = fmaf(w, bf2f(f1[k]), acc[8 + k]);
        }
      }
    }
  }
  float inv = 1.0f / (ws + 1e-6f);
  u16x8 o0, o1;
#pragma unroll
  for (int j = 0; j < 8; ++j) {
    o0[j] = (unsigned short)f2bf(acc[j] * inv);
    o1[j] = (unsigned short)f2bf(acc[8 + j] * inv);
  }
  // writes land in this voxel's own (already consumed) rec row
  *(u16x8*)&msg_bf[(long)row * 64 + seg * 16] = o0;
  *(u16x8*)&msg_bf[(long)row * 64 + seg * 16 + 8] = o1;
}

// ---- Stage 2: gate MLP + GRU; two-pass; waves_per_eu(2,2) un-caps VGPR ----
#define GST 136
#define WST 72

__global__ __launch_bounds__(512)
__attribute__((amdgpu_waves_per_eu(2, 2)))
void stage2(
    const unsigned short* __restrict__ zbf,
    const float* __restrict__ gate_w1, const float* __restrict__ gate_b1,
    const float* __restrict__ gate_w2, const float* __restrict__ gate_b2,
    const float* __restrict__ W_ih, const float* __restrict__ W_hh,
    const float* __restrict__ b_ih, const float* __restrict__ b_hh,
    const unsigned short* __restrict__ msg_bf,
    float* __restrict__ out, int ntiles)
{
  __shared__ short G1t[64 * GST];
  __shared__ short Wih_l[192 * WST];
  __shared__ short Whh_l[192 * WST];
  __shared__ float gb1s[64], gw2s[64], bihs[192], bhhs[192];
  __shared__ float gb2s;

  int t = threadIdx.x;
  for (int s = t; s < 64 * 128; s += 512) {
    int j = s & 63, k = s >> 6;
    G1t[j * GST + k] = f2bf(gate_w1[s]);
  }
  for (int s = t; s < 192 * 64; s += 512) {
    int j = s >> 6, k = s & 63;
    Wih_l[j * WST + k] = f2bf(W_ih[s]);
    Whh_l[j * WST + k] = f2bf(W_hh[s]);
  }
  if (t < 64) { gb1s[t] = gate_b1[t]; gw2s[t] = gate_w2[t]; }
  if (t < 192) { bihs[t] = b_ih[t]; bhhs[t] = b_hh[t]; }
  if (t == 0) gb2s = gate_b2[0];
  __syncthreads();

  int wid = t >> 6, lane = t & 63;
  int lr = lane & 15, lg = lane >> 4;

#pragma unroll 1
  for (int tile = blockIdx.x; tile < ntiles; tile += gridDim.x) {
    int rowbase = tile * 128 + wid * 16;
    long abase = (long)(rowbase + lr) * 64;
    bf16x8 a0 = *(const bf16x8*)&zbf[abase + lg * 8];
    bf16x8 a1 = *(const bf16x8*)&zbf[abase + 32 + lg * 8];
    bf16x8 a2 = *(const bf16x8*)&msg_bf[abase + lg * 8];
    bf16x8 a3 = *(const bf16x8*)&msg_bf[abase + 32 + lg * 8];

    // ---- pass 1: gate (only au live per ct) ----
    f32x4 usum = {0.f, 0.f, 0.f, 0.f};
#pragma unroll 1
    for (int ct = 0; ct < 4; ++ct) {
      f32x4 au = {0, 0, 0, 0};
      au = MFMA(a0, *(const bf16x8*)&G1t[(ct * 16 + lr) * GST +  0 + lg * 8], au, 0, 0, 0);
      au = MFMA(a1, *(const bf16x8*)&G1t[(ct * 16 + lr) * GST + 32 + lg * 8], au, 0, 0, 0);
      au = MFMA(a2, *(const bf16x8*)&G1t[(ct * 16 + lr) * GST + 64 + lg * 8], au, 0, 0, 0);
      au = MFMA(a3, *(const bf16x8*)&G1t[(ct * 16 + lr) * GST + 96 + lg * 8], au, 0, 0, 0);
      int c = ct * 16 + lr;
#pragma unroll
      for (int e = 0; e < 4; ++e)
        usum[e] += fmaxf(au[e] + gb1s[c], 0.0f) * gw2s[c];
    }
#pragma unroll
    for (int m = 1; m <= 8; m <<= 1)
#pragma unroll
      for (int e = 0; e < 4; ++e) {
        float v = usum[e];
        usum[e] = v + __shfl_xor(v, m, 64);
      }
    float gate[4];
#pragma unroll
    for (int e = 0; e < 4; ++e) gate[e] = sigm(usum[e] + gb2s);

    // ---- pass 2: GRU, write out immediately per ct ----
#pragma unroll 1
    for (int ct = 0; ct < 4; ++ct) {
      f32x4 air = {0,0,0,0}, aiz = {0,0,0,0}, ain = {0,0,0,0};
      f32x4 ahr = {0,0,0,0}, ahz = {0,0,0,0}, ahn = {0,0,0,0};
#pragma unroll
      for (int k2 = 0; k2 < 2; ++k2) {
        bf16x8 amg = k2 ? a3 : a2;
        bf16x8 az_ = k2 ? a1 : a0;
        int ko = k2 * 32 + lg * 8;
        air = MFMA(amg, *(const bf16x8*)&Wih_l[(      ct * 16 + lr) * WST + ko], air, 0, 0, 0);
        aiz = MFMA(amg, *(const bf16x8*)&Wih_l[( 64 + ct * 16 + lr) * WST + ko], aiz, 0, 0, 0);
        ain = MFMA(amg, *(const bf16x8*)&Wih_l[(128 + ct * 16 + lr) * WST + ko], ain, 0, 0, 0);
        ahr = MFMA(az_, *(const bf16x8*)&Whh_l[(      ct * 16 + lr) * WST + ko], ahr, 0, 0, 0);
        ahz = MFMA(az_, *(const bf16x8*)&Whh_l[( 64 + ct * 16 + lr) * WST + ko], ahz, 0, 0, 0);
        ahn = MFMA(az_, *(const bf16x8*)&Whh_l[(128 + ct * 16 + lr) * WST + ko], ahn, 0, 0, 0);
      }
      int c = ct * 16 + lr;
#pragma unroll
      for (int e = 0; e < 4; ++e) {
        float zv = bf2f(zbf[(long)(rowbase + lg * 4 + e) * 64 + c]);
        float rr = sigm(air[e] + bihs[c] + ahr[e] + bhhs[c]);
        float zg = sigm(aiz[e] + bihs[64 + c] + ahz[e] + bhhs[64 + c]);
        float nn = tanhf(ain[e] + bihs[128 + c] + rr * (ahn[e] + bhhs[128 + c]));
        float hnew = (1.0f - zg) * nn + zg * zv;
        out[(long)(rowbase + lg * 4 + e) * 64 + c] = zv + gate[e] * (hnew - zv);
      }
    }
  }
}

extern "C" void kernel_launch(void* const* d_in, const int* in_sizes, int n_in,
                              void* d_out, int out_size, void* d_ws, size_t ws_size,
                              hipStream_t stream) {
  const float* f_pts   = (const float*)d_in[0];
  const float* pts     = (const float*)d_in[1];
  const float* z_lat   = (const float*)d_in[2];
  const float* centers = (const float*)d_in[3];
  const int*   cand    = (const int*)d_in[4];
  const float* sim_w1  = (const float*)d_in[5];
  const float* sim_b1  = (const float*)d_in[6];
  const float* sim_w2  = (const float*)d_in[7];
  // d_in[8] = sim_b2: uniform softmax shift, unused
  const float* gate_w1 = (const float*)d_in[9];
  const float* gate_b1 = (const float*)d_in[10];
  const float* gate_w2 = (const float*)d_in[11];
  const float* gate_b2 = (const float*)d_in[12];
  const float* W_ih    = (const float*)d_in[13];
  const float* W_hh    = (const float*)d_in[14];
  const float* b_ih    = (const float*)d_in[15];
  const float* b_hh    = (const float*)d_in[16];

  int N = in_sizes[0] / 64;
  int M = in_sizes[2] / 64;

  int* cursor = (int*)d_ws;                                        // M i32
  unsigned* rec = (unsigned*)(cursor + M);                         // M*CAP u32
  unsigned short* msg_bf = (unsigned short*)rec;                   // alias: rec consumed by gather
  unsigned short* zbf = (unsigned short*)(rec + (size_t)M * CAP);  // M*64 bf16 (live thru stage2)
  unsigned short* fbf = zbf + (size_t)M * 64;                      // N*64 bf16
  unsigned short* HBt = fbf + (size_t)N * 64;                      // N*64 bf16 (transposed ct-packed)
  short* bfZ = (short*)(HBt + (size_t)N * 64);                     // 12*512 bf16

  prep_kernel<<<2048, 256, 0, stream>>>(z_lat, f_pts, sim_w1, sim_b1,
                                        zbf, fbf, HBt, cursor, bfZ, M);

  int nwaves = (N * 8) / (16 * TPW);                               // 4096 waves
  pair_kernel<<<nwaves / 4, 256, 0, stream>>>(pts, zbf, centers, cand,
                                              sim_w2, bfZ, HBt, cursor, rec);

  gather_kernel<<<(M * 4) / 256, 256, 0, stream>>>(rec, cursor, fbf, msg_bf, M);

  int ntiles = M / 128;
  stage2<<<512, 512, 0, stream>>>(zbf, gate_w1, gate_b1, gate_w2, gate_b2,
                                  W_ih, W_hh, b_ih, b_hh, msg_bf,
                                  (float*)d_out, ntiles);
}

// Round 12
// 112.048 us; speedup vs baseline: 2.9617x; 1.0151x over previous
//
#include <hip/hip_runtime.h>
#include <hip/hip_fp16.h>
#include <math.h>

// LatentVoxelGrid: N=65536 pts, M=131072 voxels, K=8 cand, D=64.
// prep  (z->zbf, cursor=0, pack W1z frags; blocks<1024: HBt=f@W1f+b1 MFMA + fbf)
// pair  (TPW=4, issue-all-loads-then-MFMA, batched softmax, bucket records)
// stage2(fused per-row record gather -> msg frags, gate MLP + GRU, bf16 MFMA;
//        two-pass ct loop, waves_per_eu(2,2) keeps VGPR un-capped)

typedef short bf16x8 __attribute__((ext_vector_type(8)));
typedef unsigned short u16x8 __attribute__((ext_vector_type(8)));
typedef float f32x4 __attribute__((ext_vector_type(4)));
#define MFMA __builtin_amdgcn_mfma_f32_16x16x32_bf16
#define CAP 32

__device__ __forceinline__ short f2bf(float f) {  // round-to-nearest-even
  unsigned u = __float_as_uint(f);
  unsigned r = (u + 0x7FFFu + ((u >> 16) & 1u)) >> 16;
  return (short)r;
}

__device__ __forceinline__ float bf2f(unsigned short h) {
  return __uint_as_float(((unsigned)h) << 16);
}

__device__ __forceinline__ float sigm(float x) { return 1.0f / (1.0f + __expf(-x)); }

// ---- prep: zbf, cursor=0, bfZ pack, HBt + fbf (blocks < 1024) ----
__global__ __launch_bounds__(256) void prep_kernel(
    const float* __restrict__ z, const float* __restrict__ f,
    const float* __restrict__ sim_w1, const float* __restrict__ sim_b1,
    unsigned short* __restrict__ zbf, unsigned short* __restrict__ fbf,
    unsigned short* __restrict__ HBt, int* __restrict__ cursor,
    short* __restrict__ bfZ, int M)
{
  long tid = (long)blockIdx.x * 256 + threadIdx.x;
  long nthr = (long)gridDim.x * 256;

  for (long i = tid; i < M; i += nthr) cursor[i] = 0;

  long nz = (long)M * 64;
  for (long i = tid * 8; i < nz; i += nthr * 8) {
    float4 a = *(const float4*)&z[i];
    float4 b4 = *(const float4*)&z[i + 4];
    u16x8 o;
    o[0] = (unsigned short)f2bf(a.x);  o[1] = (unsigned short)f2bf(a.y);
    o[2] = (unsigned short)f2bf(a.z);  o[3] = (unsigned short)f2bf(a.w);
    o[4] = (unsigned short)f2bf(b4.x); o[5] = (unsigned short)f2bf(b4.y);
    o[6] = (unsigned short)f2bf(b4.z); o[7] = (unsigned short)f2bf(b4.w);
    *(u16x8*)&zbf[i] = o;
  }

  if (blockIdx.x == gridDim.x - 1 && threadIdx.x < 64) {
    int lane = threadIdx.x;
    int lr = lane & 15, lg = lane >> 4;
#pragma unroll
    for (int ct = 0; ct < 4; ++ct)
#pragma unroll
      for (int kt = 0; kt < 3; ++kt) {
        bf16x8 b;
#pragma unroll
        for (int e = 0; e < 8; ++e) {
          int k = kt * 32 + lg * 8 + e;  // 0..95: [z(64) | delta(3) | pad]
          float v = (k < 67) ? sim_w1[(64 + k) * 64 + ct * 16 + lr] : 0.0f;
          b[e] = f2bf(v);
        }
        *(bf16x8*)&bfZ[(ct * 3 + kt) * 512 + lane * 8] = b;
      }
  }

  if (blockIdx.x < 1024) {  // hb: wave handles 16 point-rows; also writes fbf
    int wave = blockIdx.x * 4 + (threadIdx.x >> 6);
    int lane = threadIdx.x & 63;
    int lr = lane & 15, lg = lane >> 4;
    int n0 = wave * 16;

    bf16x8 bf[8];  // f-part B frags (sim_w1 is L2-hot)
#pragma unroll
    for (int ct = 0; ct < 4; ++ct)
#pragma unroll
      for (int kt = 0; kt < 2; ++kt) {
        bf16x8 bb;
#pragma unroll
        for (int e = 0; e < 8; ++e)
          bb[e] = f2bf(sim_w1[(kt * 32 + lg * 8 + e) * 64 + ct * 16 + lr]);
        bf[ct * 2 + kt] = bb;
      }

    bf16x8 a[2];
#pragma unroll
    for (int kt = 0; kt < 2; ++kt) {
      const float* src = &f[(long)(n0 + lr) * 64 + kt * 32 + lg * 8];
      float4 v0 = *(const float4*)src;
      float4 v1 = *(const float4*)(src + 4);
      bf16x8 t;
      t[0] = f2bf(v0.x); t[1] = f2bf(v0.y); t[2] = f2bf(v0.z); t[3] = f2bf(v0.w);
      t[4] = f2bf(v1.x); t[5] = f2bf(v1.y); t[6] = f2bf(v1.z); t[7] = f2bf(v1.w);
      a[kt] = t;
    }
    *(bf16x8*)&fbf[(long)(n0 + lr) * 64 + lg * 8] = a[0];
    *(bf16x8*)&fbf[(long)(n0 + lr) * 64 + 32 + lg * 8] = a[1];

    f32x4 acc[4] = {{0,0,0,0},{0,0,0,0},{0,0,0,0},{0,0,0,0}};
#pragma unroll
    for (int ct = 0; ct < 4; ++ct) {
      acc[ct] = MFMA(a[0], bf[ct * 2 + 0], acc[ct], 0, 0, 0);
      acc[ct] = MFMA(a[1], bf[ct * 2 + 1], acc[ct], 0, 0, 0);
    }
    float b10 = sim_b1[lr], b11 = sim_b1[16 + lr];
    float b12 = sim_b1[32 + lr], b13 = sim_b1[48 + lr];
#pragma unroll
    for (int e = 0; e < 4; ++e) {
      // HBt packed: [n][lr*4 + ct] so pair reads hb[0..3] as one 8B load
      unsigned lo = (unsigned)(unsigned short)f2bf(acc[0][e] + b10)
                  | ((unsigned)(unsigned short)f2bf(acc[1][e] + b11) << 16);
      unsigned hi = (unsigned)(unsigned short)f2bf(acc[2][e] + b12)
                  | ((unsigned)(unsigned short)f2bf(acc[3][e] + b13) << 16);
      *(uint2*)&HBt[(long)(n0 + lg * 4 + e) * 64 + lr * 4] = make_uint2(lo, hi);
    }
  }
}

// ---- pair: preload all tiles -> MFMA all -> batched softmax -> records ----
#define TPW 4
__global__ __launch_bounds__(256) void pair_kernel(
    const float* __restrict__ pts, const unsigned short* __restrict__ zbf,
    const float* __restrict__ centers, const int* __restrict__ cand_idx,
    const float* __restrict__ sim_w2, const short* __restrict__ bfZ,
    const unsigned short* __restrict__ HBt,
    int* __restrict__ cursor, unsigned* __restrict__ rec)
{
  int wave = (blockIdx.x * 256 + threadIdx.x) >> 6;
  int lane = threadIdx.x & 63;
  int lr = lane & 15, lg = lane >> 4;

  // lane owns the record of pair wave*64+lane (tile lg, row lr)
  int call = cand_idx[wave * 64 + lane];
  int slot = atomicAdd(&cursor[call], 1);  // early; hidden under compute

  bf16x8 b[12];
#pragma unroll
  for (int i = 0; i < 12; ++i) b[i] = *(const bf16x8*)&bfZ[i * 512 + lane * 8];
  float w2c[4];
#pragma unroll
  for (int ct = 0; ct < 4; ++ct) w2c[ct] = sim_w2[ct * 16 + lr];

  // ---- preload phase: ALL tiles' operands issued back-to-back ----
  int c[TPW];
  bf16x8 a0[TPW], a1[TPW], ad[TPW];
  uint2 h2[TPW];
#pragma unroll
  for (int t = 0; t < TPW; ++t) {
    c[t] = __shfl(call, t * 16 + lr, 64);
    a0[t] = *(const bf16x8*)&zbf[(long)c[t] * 64 + lg * 8];
    a1[t] = *(const bf16x8*)&zbf[(long)c[t] * 64 + 32 + lg * 8];
    h2[t] = *(const uint2*)&HBt[((long)(wave * TPW + t) * 2 + (lg >> 1)) * 64 + lr * 4];
    bf16x8 tt = {0, 0, 0, 0, 0, 0, 0, 0};
    if (lg == 0) {
      int n = (wave * TPW + t) * 2 + (lr >> 3);
      tt[0] = f2bf(pts[n * 3 + 0] - centers[c[t] * 3 + 0]);
      tt[1] = f2bf(pts[n * 3 + 1] - centers[c[t] * 3 + 1]);
      tt[2] = f2bf(pts[n * 3 + 2] - centers[c[t] * 3 + 2]);
    }
    ad[t] = tt;
  }

  // ---- MFMA + w2-dot phase ----
  f32x4 part[TPW];
#pragma unroll
  for (int t = 0; t < TPW; ++t) {
    f32x4 acc[4] = {{0,0,0,0},{0,0,0,0},{0,0,0,0},{0,0,0,0}};
#pragma unroll
    for (int ct = 0; ct < 4; ++ct) {
      acc[ct] = MFMA(a0[t], b[ct * 3 + 0], acc[ct], 0, 0, 0);
      acc[ct] = MFMA(a1[t], b[ct * 3 + 1], acc[ct], 0, 0, 0);
      acc[ct] = MFMA(ad[t], b[ct * 3 + 2], acc[ct], 0, 0, 0);
    }
    float hb[4];
    hb[0] = bf2f((unsigned short)(h2[t].x));
    hb[1] = bf2f((unsigned short)(h2[t].x >> 16));
    hb[2] = bf2f((unsigned short)(h2[t].y));
    hb[3] = bf2f((unsigned short)(h2[t].y >> 16));
    f32x4 p = {0.f, 0.f, 0.f, 0.f};
#pragma unroll
    for (int ct = 0; ct < 4; ++ct)
#pragma unroll
      for (int e = 0; e < 4; ++e)
        p[e] = fmaf(fmaxf(acc[ct][e] + hb[ct], 0.0f), w2c[ct], p[e]);
    part[t] = p;
  }

  // ---- batched softmax phase (4 independent chains) ----
  float wrow[TPW];
#pragma unroll
  for (int t = 0; t < TPW; ++t) {
    f32x4 p = part[t];
#pragma unroll
    for (int m = 1; m <= 8; m <<= 1)
#pragma unroll
      for (int e = 0; e < 4; ++e) p[e] += __shfl_xor(p[e], m, 64);
    float other[4];
#pragma unroll
    for (int e = 0; e < 4; ++e) other[e] = __shfl_xor(p[e], 16, 64);
    float mx = p[0];
#pragma unroll
    for (int e = 1; e < 4; ++e) mx = fmaxf(mx, p[e]);
#pragma unroll
    for (int e = 0; e < 4; ++e) mx = fmaxf(mx, other[e]);
    float ex[4], se = 0.f, so = 0.f;
#pragma unroll
    for (int e = 0; e < 4; ++e) {
      ex[e] = __expf((p[e] - mx) * (1.0f / 0.3f));
      se += ex[e];
      so += __expf((other[e] - mx) * (1.0f / 0.3f));
    }
    float inv = 1.0f / (se + so);
    // lane r (0..15): weight of MFMA row r (= ex[r&3]*inv from lane (r>>2)*16)
    int srcl = (lane >> 2) << 4;
    float t0 = __shfl(ex[0] * inv, srcl, 64);
    float t1 = __shfl(ex[1] * inv, srcl, 64);
    float t2 = __shfl(ex[2] * inv, srcl, 64);
    float t3 = __shfl(ex[3] * inv, srcl, 64);
    int esel = lane & 3;
    wrow[t] = esel == 0 ? t0 : esel == 1 ? t1 : esel == 2 ? t2 : t3;
  }

  // ---- epilogue: route tile lg's row-lr weight to this lane, write record ----
  float v0 = __shfl(wrow[0], lr, 64);
  float v1 = __shfl(wrow[1], lr, 64);
  float v2 = __shfl(wrow[2], lr, 64);
  float v3 = __shfl(wrow[3], lr, 64);
  float wv = lg == 0 ? v0 : lg == 1 ? v1 : lg == 2 ? v2 : v3;

  if (slot < CAP) {
    int n_pt = wave * 8 + 2 * lg + (lr >> 3);
    unsigned short wh = __half_as_ushort(__float2half(wv));
    rec[(long)call * CAP + slot] = ((unsigned)n_pt << 16) | (unsigned)wh;
  }
}

// ---- Stage 2: fused gather + gate MLP + GRU (two-pass, waves_per_eu(2,2)) ----
#define GST 136
#define WST 72

__global__ __launch_bounds__(512)
__attribute__((amdgpu_waves_per_eu(2, 2)))
void stage2(
    const unsigned short* __restrict__ zbf,
    const float* __restrict__ gate_w1, const float* __restrict__ gate_b1,
    const float* __restrict__ gate_w2, const float* __restrict__ gate_b2,
    const float* __restrict__ W_ih, const float* __restrict__ W_hh,
    const float* __restrict__ b_ih, const float* __restrict__ b_hh,
    const unsigned* __restrict__ rec, const int* __restrict__ cursor,
    const unsigned short* __restrict__ fbf,
    float* __restrict__ out, int ntiles)
{
  __shared__ short G1t[64 * GST];
  __shared__ short Wih_l[192 * WST];
  __shared__ short Whh_l[192 * WST];
  __shared__ float gb1s[64], gw2s[64], bihs[192], bhhs[192];
  __shared__ float gb2s;

  int t = threadIdx.x;
  for (int s = t; s < 64 * 128; s += 512) {
    int j = s & 63, k = s >> 6;
    G1t[j * GST + k] = f2bf(gate_w1[s]);
  }
  for (int s = t; s < 192 * 64; s += 512) {
    int j = s >> 6, k = s & 63;
    Wih_l[j * WST + k] = f2bf(W_ih[s]);
    Whh_l[j * WST + k] = f2bf(W_hh[s]);
  }
  if (t < 64) { gb1s[t] = gate_b1[t]; gw2s[t] = gate_w2[t]; }
  if (t < 192) { bihs[t] = b_ih[t]; bhhs[t] = b_hh[t]; }
  if (t == 0) gb2s = gate_b2[0];
  __syncthreads();

  int wid = t >> 6, lane = t & 63;
  int lr = lane & 15, lg = lane >> 4;

#pragma unroll 1
  for (int tile = blockIdx.x; tile < ntiles; tile += gridDim.x) {
    int rowbase = tile * 128 + wid * 16;
    int myrow = rowbase + lr;
    long abase = (long)myrow * 64;
    bf16x8 a0 = *(const bf16x8*)&zbf[abase + lg * 8];
    bf16x8 a1 = *(const bf16x8*)&zbf[abase + 32 + lg * 8];

    // ---- fused gather: lane builds its own msg fragments for row myrow ----
    int cnt = cursor[myrow];
    cnt = cnt < CAP ? cnt : CAP;
    const unsigned* rp = &rec[(long)myrow * CAP];
    float accA[8], accB[8];
#pragma unroll
    for (int k = 0; k < 8; ++k) { accA[k] = 0.f; accB[k] = 0.f; }
    float ws = 0.f;
#pragma unroll 1
    for (int i0 = 0; i0 < cnt; i0 += 4) {
      uint4 r4 = *(const uint4*)&rp[i0];
#pragma unroll
      for (int j = 0; j < 4; ++j) {
        unsigned r = j == 0 ? r4.x : j == 1 ? r4.y : j == 2 ? r4.z : r4.w;
        if (i0 + j < cnt) {
          float w = __half2float(__ushort_as_half((unsigned short)(r & 0xffffu)));
          int n = r >> 16;
          ws += w;
          u16x8 fA = *(const u16x8*)&fbf[(long)n * 64 + lg * 8];
          u16x8 fB = *(const u16x8*)&fbf[(long)n * 64 + 32 + lg * 8];
#pragma unroll
          for (int k = 0; k < 8; ++k) {
            accA[k] = fmaf(w, bf2f(fA[k]), accA[k]);
            accB[k] = fmaf(w, bf2f(fB[k]), accB[k]);
          }
        }
      }
    }
    float minv = 1.0f / (ws + 1e-6f);
    bf16x8 a2, a3;
#pragma unroll
    for (int k = 0; k < 8; ++k) {
      a2[k] = f2bf(accA[k] * minv);
      a3[k] = f2bf(accB[k] * minv);
    }

    // ---- pass 1: gate (only au live per ct) ----
    f32x4 usum = {0.f, 0.f, 0.f, 0.f};
#pragma unroll 1
    for (int ct = 0; ct < 4; ++ct) {
      f32x4 au = {0, 0, 0, 0};
      au = MFMA(a0, *(const bf16x8*)&G1t[(ct * 16 + lr) * GST +  0 + lg * 8], au, 0, 0, 0);
      au = MFMA(a1, *(const bf16x8*)&G1t[(ct * 16 + lr) * GST + 32 + lg * 8], au, 0, 0, 0);
      au = MFMA(a2, *(const bf16x8*)&G1t[(ct * 16 + lr) * GST + 64 + lg * 8], au, 0, 0, 0);
      au = MFMA(a3, *(const bf16x8*)&G1t[(ct * 16 + lr) * GST + 96 + lg * 8], au, 0, 0, 0);
      int c = ct * 16 + lr;
#pragma unroll
      for (int e = 0; e < 4; ++e)
        usum[e] += fmaxf(au[e] + gb1s[c], 0.0f) * gw2s[c];
    }
#pragma unroll
    for (int m = 1; m <= 8; m <<= 1)
#pragma unroll
      for (int e = 0; e < 4; ++e) {
        float v = usum[e];
        usum[e] = v + __shfl_xor(v, m, 64);
      }
    float gate[4];
#pragma unroll
    for (int e = 0; e < 4; ++e) gate[e] = sigm(usum[e] + gb2s);

    // ---- pass 2: GRU, write out immediately per ct ----
#pragma unroll 1
    for (int ct = 0; ct < 4; ++ct) {
      f32x4 air = {0,0,0,0}, aiz = {0,0,0,0}, ain = {0,0,0,0};
      f32x4 ahr = {0,0,0,0}, ahz = {0,0,0,0}, ahn = {0,0,0,0};
#pragma unroll
      for (int k2 = 0; k2 < 2; ++k2) {
        bf16x8 amg = k2 ? a3 : a2;
        bf16x8 az_ = k2 ? a1 : a0;
        int ko = k2 * 32 + lg * 8;
        air = MFMA(amg, *(const bf16x8*)&Wih_l[(      ct * 16 + lr) * WST + ko], air, 0, 0, 0);
        aiz = MFMA(amg, *(const bf16x8*)&Wih_l[( 64 + ct * 16 + lr) * WST + ko], aiz, 0, 0, 0);
        ain = MFMA(amg, *(const bf16x8*)&Wih_l[(128 + ct * 16 + lr) * WST + ko], ain, 0, 0, 0);
        ahr = MFMA(az_, *(const bf16x8*)&Whh_l[(      ct * 16 + lr) * WST + ko], ahr, 0, 0, 0);
        ahz = MFMA(az_, *(const bf16x8*)&Whh_l[( 64 + ct * 16 + lr) * WST + ko], ahz, 0, 0, 0);
        ahn = MFMA(az_, *(const bf16x8*)&Whh_l[(128 + ct * 16 + lr) * WST + ko], ahn, 0, 0, 0);
      }
      int c = ct * 16 + lr;
#pragma unroll
      for (int e = 0; e < 4; ++e) {
        float zv = bf2f(zbf[(long)(rowbase + lg * 4 + e) * 64 + c]);
        float rr = sigm(air[e] + bihs[c] + ahr[e] + bhhs[c]);
        float zg = sigm(aiz[e] + bihs[64 + c] + ahz[e] + bhhs[64 + c]);
        float nn = tanhf(ain[e] + bihs[128 + c] + rr * (ahn[e] + bhhs[128 + c]));
        float hnew = (1.0f - zg) * nn + zg * zv;
        out[(long)(rowbase + lg * 4 + e) * 64 + c] = zv + gate[e] * (hnew - zv);
      }
    }
  }
}

extern "C" void kernel_launch(void* const* d_in, const int* in_sizes, int n_in,
                              void* d_out, int out_size, void* d_ws, size_t ws_size,
                              hipStream_t stream) {
  const float* f_pts   = (const float*)d_in[0];
  const float* pts     = (const float*)d_in[1];
  const float* z_lat   = (const float*)d_in[2];
  const float* centers = (const float*)d_in[3];
  const int*   cand    = (const int*)d_in[4];
  const float* sim_w1  = (const float*)d_in[5];
  const float* sim_b1  = (const float*)d_in[6];
  const float* sim_w2  = (const float*)d_in[7];
  // d_in[8] = sim_b2: uniform softmax shift, unused
  const float* gate_w1 = (const float*)d_in[9];
  const float* gate_b1 = (const float*)d_in[10];
  const float* gate_w2 = (const float*)d_in[11];
  const float* gate_b2 = (const float*)d_in[12];
  const float* W_ih    = (const float*)d_in[13];
  const float* W_hh    = (const float*)d_in[14];
  const float* b_ih    = (const float*)d_in[15];
  const float* b_hh    = (const float*)d_in[16];

  int N = in_sizes[0] / 64;
  int M = in_sizes[2] / 64;

  int* cursor = (int*)d_ws;                                        // M i32
  unsigned* rec = (unsigned*)(cursor + M);                         // M*CAP u32
  unsigned short* zbf = (unsigned short*)(rec + (size_t)M * CAP);  // M*64 bf16
  unsigned short* fbf = zbf + (size_t)M * 64;                      // N*64 bf16
  unsigned short* HBt = fbf + (size_t)N * 64;                      // N*64 bf16 (ct-packed)
  short* bfZ = (short*)(HBt + (size_t)N * 64);                     // 12*512 bf16

  prep_kernel<<<2048, 256, 0, stream>>>(z_lat, f_pts, sim_w1, sim_b1,
                                        zbf, fbf, HBt, cursor, bfZ, M);

  int nwaves = (N * 8) / (16 * TPW);                               // 8192 waves
  pair_kernel<<<nwaves / 4, 256, 0, stream>>>(pts, zbf, centers, cand,
                                              sim_w2, bfZ, HBt, cursor, rec);

  int ntiles = M / 128;
  stage2<<<512, 512, 0, stream>>>(zbf, gate_w1, gate_b1, gate_w2, gate_b2,
                                  W_ih, W_hh, b_ih, b_hh, rec, cursor, fbf,
                                  (float*)d_out, ntiles);
}

// Round 13
// 110.491 us; speedup vs baseline: 3.0034x; 1.0141x over previous
//
#include <hip/hip_runtime.h>
#include <hip/hip_fp16.h>
#include <math.h>

// LatentVoxelGrid: N=65536 pts, M=131072 voxels, K=8 cand, D=64.
// prep  (z->zbf, cursor=0, pack W1z frags; blocks<1024: HBt=f@W1f+b1 MFMA + fbf)
// pair  (TPW=4, issue-all-loads-then-MFMA, batched softmax, bucket records)
// gather(per-voxel Sum w*f / Sum w -> normalized bf16 msg; msg aliases rec)
// stage2(gate MLP + GRU, bf16 MFMA; two-pass ct loop, waves_per_eu(2,2))

typedef short bf16x8 __attribute__((ext_vector_type(8)));
typedef unsigned short u16x8 __attribute__((ext_vector_type(8)));
typedef float f32x4 __attribute__((ext_vector_type(4)));
#define MFMA __builtin_amdgcn_mfma_f32_16x16x32_bf16
#define CAP 32

__device__ __forceinline__ short f2bf(float f) {  // round-to-nearest-even
  unsigned u = __float_as_uint(f);
  unsigned r = (u + 0x7FFFu + ((u >> 16) & 1u)) >> 16;
  return (short)r;
}

__device__ __forceinline__ float bf2f(unsigned short h) {
  return __uint_as_float(((unsigned)h) << 16);
}

__device__ __forceinline__ float sigm(float x) { return 1.0f / (1.0f + __expf(-x)); }

// ---- prep: zbf, cursor=0, bfZ pack, HBt + fbf (blocks < 1024) ----
__global__ __launch_bounds__(256) void prep_kernel(
    const float* __restrict__ z, const float* __restrict__ f,
    const float* __restrict__ sim_w1, const float* __restrict__ sim_b1,
    unsigned short* __restrict__ zbf, unsigned short* __restrict__ fbf,
    unsigned short* __restrict__ HBt, int* __restrict__ cursor,
    short* __restrict__ bfZ, int M)
{
  long tid = (long)blockIdx.x * 256 + threadIdx.x;
  long nthr = (long)gridDim.x * 256;

  for (long i = tid; i < M; i += nthr) cursor[i] = 0;

  long nz = (long)M * 64;
  for (long i = tid * 8; i < nz; i += nthr * 8) {
    float4 a = *(const float4*)&z[i];
    float4 b4 = *(const float4*)&z[i + 4];
    u16x8 o;
    o[0] = (unsigned short)f2bf(a.x);  o[1] = (unsigned short)f2bf(a.y);
    o[2] = (unsigned short)f2bf(a.z);  o[3] = (unsigned short)f2bf(a.w);
    o[4] = (unsigned short)f2bf(b4.x); o[5] = (unsigned short)f2bf(b4.y);
    o[6] = (unsigned short)f2bf(b4.z); o[7] = (unsigned short)f2bf(b4.w);
    *(u16x8*)&zbf[i] = o;
  }

  if (blockIdx.x == gridDim.x - 1 && threadIdx.x < 64) {
    int lane = threadIdx.x;
    int lr = lane & 15, lg = lane >> 4;
#pragma unroll
    for (int ct = 0; ct < 4; ++ct)
#pragma unroll
      for (int kt = 0; kt < 3; ++kt) {
        bf16x8 b;
#pragma unroll
        for (int e = 0; e < 8; ++e) {
          int k = kt * 32 + lg * 8 + e;  // 0..95: [z(64) | delta(3) | pad]
          float v = (k < 67) ? sim_w1[(64 + k) * 64 + ct * 16 + lr] : 0.0f;
          b[e] = f2bf(v);
        }
        *(bf16x8*)&bfZ[(ct * 3 + kt) * 512 + lane * 8] = b;
      }
  }

  if (blockIdx.x < 1024) {  // hb: wave handles 16 point-rows; also writes fbf
    int wave = blockIdx.x * 4 + (threadIdx.x >> 6);
    int lane = threadIdx.x & 63;
    int lr = lane & 15, lg = lane >> 4;
    int n0 = wave * 16;

    bf16x8 bf[8];  // f-part B frags (sim_w1 is L2-hot)
#pragma unroll
    for (int ct = 0; ct < 4; ++ct)
#pragma unroll
      for (int kt = 0; kt < 2; ++kt) {
        bf16x8 bb;
#pragma unroll
        for (int e = 0; e < 8; ++e)
          bb[e] = f2bf(sim_w1[(kt * 32 + lg * 8 + e) * 64 + ct * 16 + lr]);
        bf[ct * 2 + kt] = bb;
      }

    bf16x8 a[2];
#pragma unroll
    for (int kt = 0; kt < 2; ++kt) {
      const float* src = &f[(long)(n0 + lr) * 64 + kt * 32 + lg * 8];
      float4 v0 = *(const float4*)src;
      float4 v1 = *(const float4*)(src + 4);
      bf16x8 t;
      t[0] = f2bf(v0.x); t[1] = f2bf(v0.y); t[2] = f2bf(v0.z); t[3] = f2bf(v0.w);
      t[4] = f2bf(v1.x); t[5] = f2bf(v1.y); t[6] = f2bf(v1.z); t[7] = f2bf(v1.w);
      a[kt] = t;
    }
    *(bf16x8*)&fbf[(long)(n0 + lr) * 64 + lg * 8] = a[0];
    *(bf16x8*)&fbf[(long)(n0 + lr) * 64 + 32 + lg * 8] = a[1];

    f32x4 acc[4] = {{0,0,0,0},{0,0,0,0},{0,0,0,0},{0,0,0,0}};
#pragma unroll
    for (int ct = 0; ct < 4; ++ct) {
      acc[ct] = MFMA(a[0], bf[ct * 2 + 0], acc[ct], 0, 0, 0);
      acc[ct] = MFMA(a[1], bf[ct * 2 + 1], acc[ct], 0, 0, 0);
    }
    float b10 = sim_b1[lr], b11 = sim_b1[16 + lr];
    float b12 = sim_b1[32 + lr], b13 = sim_b1[48 + lr];
#pragma unroll
    for (int e = 0; e < 4; ++e) {
      // HBt packed: [n][lr*4 + ct] so pair reads hb[0..3] as one 8B load
      unsigned lo = (unsigned)(unsigned short)f2bf(acc[0][e] + b10)
                  | ((unsigned)(unsigned short)f2bf(acc[1][e] + b11) << 16);
      unsigned hi = (unsigned)(unsigned short)f2bf(acc[2][e] + b12)
                  | ((unsigned)(unsigned short)f2bf(acc[3][e] + b13) << 16);
      *(uint2*)&HBt[(long)(n0 + lg * 4 + e) * 64 + lr * 4] = make_uint2(lo, hi);
    }
  }
}

// ---- pair: preload all tiles -> MFMA all -> batched softmax -> records ----
#define TPW 4
__global__ __launch_bounds__(256) void pair_kernel(
    const float* __restrict__ pts, const unsigned short* __restrict__ zbf,
    const float* __restrict__ centers, const int* __restrict__ cand_idx,
    const float* __restrict__ sim_w2, const short* __restrict__ bfZ,
    const unsigned short* __restrict__ HBt,
    int* __restrict__ cursor, unsigned* __restrict__ rec)
{
  int wave = (blockIdx.x * 256 + threadIdx.x) >> 6;
  int lane = threadIdx.x & 63;
  int lr = lane & 15, lg = lane >> 4;

  // lane owns the record of pair wave*64+lane (tile lg, row lr)
  int call = cand_idx[wave * 64 + lane];
  int slot = atomicAdd(&cursor[call], 1);  // early; hidden under compute

  bf16x8 b[12];
#pragma unroll
  for (int i = 0; i < 12; ++i) b[i] = *(const bf16x8*)&bfZ[i * 512 + lane * 8];
  float w2c[4];
#pragma unroll
  for (int ct = 0; ct < 4; ++ct) w2c[ct] = sim_w2[ct * 16 + lr];

  // ---- preload phase: ALL tiles' operands issued back-to-back ----
  int c[TPW];
  bf16x8 a0[TPW], a1[TPW], ad[TPW];
  uint2 h2[TPW];
#pragma unroll
  for (int t = 0; t < TPW; ++t) {
    c[t] = __shfl(call, t * 16 + lr, 64);
    a0[t] = *(const bf16x8*)&zbf[(long)c[t] * 64 + lg * 8];
    a1[t] = *(const bf16x8*)&zbf[(long)c[t] * 64 + 32 + lg * 8];
    h2[t] = *(const uint2*)&HBt[((long)(wave * TPW + t) * 2 + (lg >> 1)) * 64 + lr * 4];
    bf16x8 tt = {0, 0, 0, 0, 0, 0, 0, 0};
    if (lg == 0) {
      int n = (wave * TPW + t) * 2 + (lr >> 3);
      tt[0] = f2bf(pts[n * 3 + 0] - centers[c[t] * 3 + 0]);
      tt[1] = f2bf(pts[n * 3 + 1] - centers[c[t] * 3 + 1]);
      tt[2] = f2bf(pts[n * 3 + 2] - centers[c[t] * 3 + 2]);
    }
    ad[t] = tt;
  }

  // ---- MFMA + w2-dot phase ----
  f32x4 part[TPW];
#pragma unroll
  for (int t = 0; t < TPW; ++t) {
    f32x4 acc[4] = {{0,0,0,0},{0,0,0,0},{0,0,0,0},{0,0,0,0}};
#pragma unroll
    for (int ct = 0; ct < 4; ++ct) {
      acc[ct] = MFMA(a0[t], b[ct * 3 + 0], acc[ct], 0, 0, 0);
      acc[ct] = MFMA(a1[t], b[ct * 3 + 1], acc[ct], 0, 0, 0);
      acc[ct] = MFMA(ad[t], b[ct * 3 + 2], acc[ct], 0, 0, 0);
    }
    float hb[4];
    hb[0] = bf2f((unsigned short)(h2[t].x));
    hb[1] = bf2f((unsigned short)(h2[t].x >> 16));
    hb[2] = bf2f((unsigned short)(h2[t].y));
    hb[3] = bf2f((unsigned short)(h2[t].y >> 16));
    f32x4 p = {0.f, 0.f, 0.f, 0.f};
#pragma unroll
    for (int ct = 0; ct < 4; ++ct)
#pragma unroll
      for (int e = 0; e < 4; ++e)
        p[e] = fmaf(fmaxf(acc[ct][e] + hb[ct], 0.0f), w2c[ct], p[e]);
    part[t] = p;
  }

  // ---- batched softmax phase (4 independent chains) ----
  float wrow[TPW];
#pragma unroll
  for (int t = 0; t < TPW; ++t) {
    f32x4 p = part[t];
#pragma unroll
    for (int m = 1; m <= 8; m <<= 1)
#pragma unroll
      for (int e = 0; e < 4; ++e) p[e] += __shfl_xor(p[e], m, 64);
    float other[4];
#pragma unroll
    for (int e = 0; e < 4; ++e) other[e] = __shfl_xor(p[e], 16, 64);
    float mx = p[0];
#pragma unroll
    for (int e = 1; e < 4; ++e) mx = fmaxf(mx, p[e]);
#pragma unroll
    for (int e = 0; e < 4; ++e) mx = fmaxf(mx, other[e]);
    float ex[4], se = 0.f, so = 0.f;
#pragma unroll
    for (int e = 0; e < 4; ++e) {
      ex[e] = __expf((p[e] - mx) * (1.0f / 0.3f));
      se += ex[e];
      so += __expf((other[e] - mx) * (1.0f / 0.3f));
    }
    float inv = 1.0f / (se + so);
    // lane r (0..15): weight of MFMA row r (= ex[r&3]*inv from lane (r>>2)*16)
    int srcl = (lane >> 2) << 4;
    float t0 = __shfl(ex[0] * inv, srcl, 64);
    float t1 = __shfl(ex[1] * inv, srcl, 64);
    float t2 = __shfl(ex[2] * inv, srcl, 64);
    float t3 = __shfl(ex[3] * inv, srcl, 64);
    int esel = lane & 3;
    wrow[t] = esel == 0 ? t0 : esel == 1 ? t1 : esel == 2 ? t2 : t3;
  }

  // ---- epilogue: route tile lg's row-lr weight to this lane, write record ----
  float v0 = __shfl(wrow[0], lr, 64);
  float v1 = __shfl(wrow[1], lr, 64);
  float v2 = __shfl(wrow[2], lr, 64);
  float v3 = __shfl(wrow[3], lr, 64);
  float wv = lg == 0 ? v0 : lg == 1 ? v1 : lg == 2 ? v2 : v3;

  if (slot < CAP) {
    int n_pt = wave * 8 + 2 * lg + (lr >> 3);
    unsigned short wh = __half_as_ushort(__float2half(wv));
    rec[(long)call * CAP + slot] = ((unsigned)n_pt << 16) | (unsigned)wh;
  }
}

// ---- gather: msg[v] = (Sum w*f[n]) / (Sum w + eps); msg ALIASES rec rows ----
__global__ __launch_bounds__(256) void gather_kernel(
    const unsigned* __restrict__ rec, const int* __restrict__ cursor,
    const unsigned short* __restrict__ fbf, unsigned short* __restrict__ msg_bf,
    int mvox)
{
  int tid = blockIdx.x * 256 + threadIdx.x;
  int row = tid >> 2, seg = tid & 3;  // 4 threads per voxel, 16 cols each
  if (row >= mvox) return;

  int cnt = cursor[row];
  cnt = cnt < CAP ? cnt : CAP;
  const unsigned* rp = &rec[(long)row * CAP];

  float acc[16];
#pragma unroll
  for (int j = 0; j < 16; ++j) acc[j] = 0.f;
  float ws = 0.f;

  for (int i0 = 0; i0 < cnt; i0 += 4) {   // rec row chunked 4-wide: fbf loads overlap
    uint4 r4 = *(const uint4*)&rp[i0];
    unsigned rr0 = r4.x, rr1 = r4.y, rr2 = r4.z, rr3 = r4.w;
#pragma unroll
    for (int j = 0; j < 4; ++j) {
      unsigned r = j == 0 ? rr0 : j == 1 ? rr1 : j == 2 ? rr2 : rr3;
      if (i0 + j < cnt) {
        float w = __half2float(__ushort_as_half((unsigned short)(r & 0xffffu)));
        int n = r >> 16;
        ws += w;
        const u16x8* fp = (const u16x8*)&fbf[(long)n * 64 + seg * 16];
        u16x8 f0 = fp[0], f1 = fp[1];
#pragma unroll
        for (int k = 0; k < 8; ++k) {
          acc[k]     = fmaf(w, bf2f(f0[k]), acc[k]);
          acc[8 + k] = fmaf(w, bf2f(f1[k]), acc[8 + k]);
        }
      }
    }
  }
  float inv = 1.0f / (ws + 1e-6f);
  u16x8 o0, o1;
#pragma unroll
  for (int j = 0; j < 8; ++j) {
    o0[j] = (unsigned short)f2bf(acc[j] * inv);
    o1[j] = (unsigned short)f2bf(acc[8 + j] * inv);
  }
  // writes land in this voxel's own (already consumed) rec row
  *(u16x8*)&msg_bf[(long)row * 64 + seg * 16] = o0;
  *(u16x8*)&msg_bf[(long)row * 64 + seg * 16 + 8] = o1;
}

// ---- Stage 2: gate MLP + GRU; two-pass; waves_per_eu(2,2) un-caps VGPR ----
#define GST 136
#define WST 72

__global__ __launch_bounds__(512)
__attribute__((amdgpu_waves_per_eu(2, 2)))
void stage2(
    const unsigned short* __restrict__ zbf,
    const float* __restrict__ gate_w1, const float* __restrict__ gate_b1,
    const float* __restrict__ gate_w2, const float* __restrict__ gate_b2,
    const float* __restrict__ W_ih, const float* __restrict__ W_hh,
    const float* __restrict__ b_ih, const float* __restrict__ b_hh,
    const unsigned short* __restrict__ msg_bf,
    float* __restrict__ out, int ntiles)
{
  __shared__ short G1t[64 * GST];
  __shared__ short Wih_l[192 * WST];
  __shared__ short Whh_l[192 * WST];
  __shared__ float gb1s[64], gw2s[64], bihs[192], bhhs[192];
  __shared__ float gb2s;

  int t = threadIdx.x;
  for (int s = t; s < 64 * 128; s += 512) {
    int j = s & 63, k = s >> 6;
    G1t[j * GST + k] = f2bf(gate_w1[s]);
  }
  for (int s = t; s < 192 * 64; s += 512) {
    int j = s >> 6, k = s & 63;
    Wih_l[j * WST + k] = f2bf(W_ih[s]);
    Whh_l[j * WST + k] = f2bf(W_hh[s]);
  }
  if (t < 64) { gb1s[t] = gate_b1[t]; gw2s[t] = gate_w2[t]; }
  if (t < 192) { bihs[t] = b_ih[t]; bhhs[t] = b_hh[t]; }
  if (t == 0) gb2s = gate_b2[0];
  __syncthreads();

  int wid = t >> 6, lane = t & 63;
  int lr = lane & 15, lg = lane >> 4;

#pragma unroll 1
  for (int tile = blockIdx.x; tile < ntiles; tile += gridDim.x) {
    int rowbase = tile * 128 + wid * 16;
    long abase = (long)(rowbase + lr) * 64;
    bf16x8 a0 = *(const bf16x8*)&zbf[abase + lg * 8];
    bf16x8 a1 = *(const bf16x8*)&zbf[abase + 32 + lg * 8];
    bf16x8 a2 = *(const bf16x8*)&msg_bf[abase + lg * 8];
    bf16x8 a3 = *(const bf16x8*)&msg_bf[abase + 32 + lg * 8];

    // ---- pass 1: gate (only au live per ct) ----
    f32x4 usum = {0.f, 0.f, 0.f, 0.f};
#pragma unroll 1
    for (int ct = 0; ct < 4; ++ct) {
      f32x4 au = {0, 0, 0, 0};
      au = MFMA(a0, *(const bf16x8*)&G1t[(ct * 16 + lr) * GST +  0 + lg * 8], au, 0, 0, 0);
      au = MFMA(a1, *(const bf16x8*)&G1t[(ct * 16 + lr) * GST + 32 + lg * 8], au, 0, 0, 0);
      au = MFMA(a2, *(const bf16x8*)&G1t[(ct * 16 + lr) * GST + 64 + lg * 8], au, 0, 0, 0);
      au = MFMA(a3, *(const bf16x8*)&G1t[(ct * 16 + lr) * GST + 96 + lg * 8], au, 0, 0, 0);
      int c = ct * 16 + lr;
#pragma unroll
      for (int e = 0; e < 4; ++e)
        usum[e] += fmaxf(au[e] + gb1s[c], 0.0f) * gw2s[c];
    }
#pragma unroll
    for (int m = 1; m <= 8; m <<= 1)
#pragma unroll
      for (int e = 0; e < 4; ++e) {
        float v = usum[e];
        usum[e] = v + __shfl_xor(v, m, 64);
      }
    float gate[4];
#pragma unroll
    for (int e = 0; e < 4; ++e) gate[e] = sigm(usum[e] + gb2s);

    // ---- pass 2: GRU, write out immediately per ct ----
#pragma unroll 1
    for (int ct = 0; ct < 4; ++ct) {
      f32x4 air = {0,0,0,0}, aiz = {0,0,0,0}, ain = {0,0,0,0};
      f32x4 ahr = {0,0,0,0}, ahz = {0,0,0,0}, ahn = {0,0,0,0};
#pragma unroll
      for (int k2 = 0; k2 < 2; ++k2) {
        bf16x8 amg = k2 ? a3 : a2;
        bf16x8 az_ = k2 ? a1 : a0;
        int ko = k2 * 32 + lg * 8;
        air = MFMA(amg, *(const bf16x8*)&Wih_l[(      ct * 16 + lr) * WST + ko], air, 0, 0, 0);
        aiz = MFMA(amg, *(const bf16x8*)&Wih_l[( 64 + ct * 16 + lr) * WST + ko], aiz, 0, 0, 0);
        ain = MFMA(amg, *(const bf16x8*)&Wih_l[(128 + ct * 16 + lr) * WST + ko], ain, 0, 0, 0);
        ahr = MFMA(az_, *(const bf16x8*)&Whh_l[(      ct * 16 + lr) * WST + ko], ahr, 0, 0, 0);
        ahz = MFMA(az_, *(const bf16x8*)&Whh_l[( 64 + ct * 16 + lr) * WST + ko], ahz, 0, 0, 0);
        ahn = MFMA(az_, *(const bf16x8*)&Whh_l[(128 + ct * 16 + lr) * WST + ko], ahn, 0, 0, 0);
      }
      int c = ct * 16 + lr;
#pragma unroll
      for (int e = 0; e < 4; ++e) {
        float zv = bf2f(zbf[(long)(rowbase + lg * 4 + e) * 64 + c]);
        float rr = sigm(air[e] + bihs[c] + ahr[e] + bhhs[c]);
        float zg = sigm(aiz[e] + bihs[64 + c] + ahz[e] + bhhs[64 + c]);
        float nn = tanhf(ain[e] + bihs[128 + c] + rr * (ahn[e] + bhhs[128 + c]));
        float hnew = (1.0f - zg) * nn + zg * zv;
        out[(long)(rowbase + lg * 4 + e) * 64 + c] = zv + gate[e] * (hnew - zv);
      }
    }
  }
}

extern "C" void kernel_launch(void* const* d_in, const int* in_sizes, int n_in,
                              void* d_out, int out_size, void* d_ws, size_t ws_size,
                              hipStream_t stream) {
  const float* f_pts   = (const float*)d_in[0];
  const float* pts     = (const float*)d_in[1];
  const float* z_lat   = (const float*)d_in[2];
  const float* centers = (const float*)d_in[3];
  const int*   cand    = (const int*)d_in[4];
  const float* sim_w1  = (const float*)d_in[5];
  const float* sim_b1  = (const float*)d_in[6];
  const float* sim_w2  = (const float*)d_in[7];
  // d_in[8] = sim_b2: uniform softmax shift, unused
  const float* gate_w1 = (const float*)d_in[9];
  const float* gate_b1 = (const float*)d_in[10];
  const float* gate_w2 = (const float*)d_in[11];
  const float* gate_b2 = (const float*)d_in[12];
  const float* W_ih    = (const float*)d_in[13];
  const float* W_hh    = (const float*)d_in[14];
  const float* b_ih    = (const float*)d_in[15];
  const float* b_hh    = (const float*)d_in[16];

  int N = in_sizes[0] / 64;
  int M = in_sizes[2] / 64;

  int* cursor = (int*)d_ws;                                        // M i32
  unsigned* rec = (unsigned*)(cursor + M);                         // M*CAP u32
  unsigned short* msg_bf = (unsigned short*)rec;                   // alias: rec consumed by gather
  unsigned short* zbf = (unsigned short*)(rec + (size_t)M * CAP);  // M*64 bf16 (live thru stage2)
  unsigned short* fbf = zbf + (size_t)M * 64;                      // N*64 bf16
  unsigned short* HBt = fbf + (size_t)N * 64;                      // N*64 bf16 (ct-packed)
  short* bfZ = (short*)(HBt + (size_t)N * 64);                     // 12*512 bf16

  prep_kernel<<<2048, 256, 0, stream>>>(z_lat, f_pts, sim_w1, sim_b1,
                                        zbf, fbf, HBt, cursor, bfZ, M);

  int nwaves = (N * 8) / (16 * TPW);                               // 8192 waves
  pair_kernel<<<nwaves / 4, 256, 0, stream>>>(pts, zbf, centers, cand,
                                              sim_w2, bfZ, HBt, cursor, rec);

  gather_kernel<<<(M * 4) / 256, 256, 0, stream>>>(rec, cursor, fbf, msg_bf, M);

  int ntiles = M / 128;
  stage2<<<512, 512, 0, stream>>>(zbf, gate_w1, gate_b1, gate_w2, gate_b2,
                                  W_ih, W_hh, b_ih, b_hh, msg_bf,
                                  (float*)d_out, ntiles);
}

// Round 14
// 107.188 us; speedup vs baseline: 3.0960x; 1.0308x over previous
//
#include <hip/hip_runtime.h>
#include <hip/hip_fp16.h>
#include <math.h>

// LatentVoxelGrid: N=65536 pts, M=131072 voxels, K=8 cand, D=64.
// prep  (z->zbf, cursor=0, pack W1z frags; blocks<1024: HBt=f@W1f+b1 MFMA + fbf)
// pair  (TPW=4, preload-all -> MFMA -> batched softmax; cursor atomic moved to
//        EPILOGUE — in-order vmcnt retirement made an early atomic block all
//        later loads' waits)
// gather(per-voxel Sum w*f / Sum w -> normalized bf16 msg; msg aliases rec)
// stage2(gate MLP + GRU, bf16 MFMA; two-pass ct loop, waves_per_eu(2) min-only:
//        VGPR cap 256 without limiting residency to 1 block/CU)

typedef short bf16x8 __attribute__((ext_vector_type(8)));
typedef unsigned short u16x8 __attribute__((ext_vector_type(8)));
typedef float f32x4 __attribute__((ext_vector_type(4)));
#define MFMA __builtin_amdgcn_mfma_f32_16x16x32_bf16
#define CAP 32

__device__ __forceinline__ short f2bf(float f) {  // round-to-nearest-even
  unsigned u = __float_as_uint(f);
  unsigned r = (u + 0x7FFFu + ((u >> 16) & 1u)) >> 16;
  return (short)r;
}

__device__ __forceinline__ float bf2f(unsigned short h) {
  return __uint_as_float(((unsigned)h) << 16);
}

__device__ __forceinline__ float sigm(float x) { return 1.0f / (1.0f + __expf(-x)); }

// ---- prep: zbf, cursor=0, bfZ pack, HBt + fbf (blocks < 1024) ----
__global__ __launch_bounds__(256) void prep_kernel(
    const float* __restrict__ z, const float* __restrict__ f,
    const float* __restrict__ sim_w1, const float* __restrict__ sim_b1,
    unsigned short* __restrict__ zbf, unsigned short* __restrict__ fbf,
    unsigned short* __restrict__ HBt, int* __restrict__ cursor,
    short* __restrict__ bfZ, int M)
{
  long tid = (long)blockIdx.x * 256 + threadIdx.x;
  long nthr = (long)gridDim.x * 256;

  for (long i = tid; i < M; i += nthr) cursor[i] = 0;

  long nz = (long)M * 64;
  for (long i = tid * 8; i < nz; i += nthr * 8) {
    float4 a = *(const float4*)&z[i];
    float4 b4 = *(const float4*)&z[i + 4];
    u16x8 o;
    o[0] = (unsigned short)f2bf(a.x);  o[1] = (unsigned short)f2bf(a.y);
    o[2] = (unsigned short)f2bf(a.z);  o[3] = (unsigned short)f2bf(a.w);
    o[4] = (unsigned short)f2bf(b4.x); o[5] = (unsigned short)f2bf(b4.y);
    o[6] = (unsigned short)f2bf(b4.z); o[7] = (unsigned short)f2bf(b4.w);
    *(u16x8*)&zbf[i] = o;
  }

  if (blockIdx.x == gridDim.x - 1 && threadIdx.x < 64) {
    int lane = threadIdx.x;
    int lr = lane & 15, lg = lane >> 4;
#pragma unroll
    for (int ct = 0; ct < 4; ++ct)
#pragma unroll
      for (int kt = 0; kt < 3; ++kt) {
        bf16x8 b;
#pragma unroll
        for (int e = 0; e < 8; ++e) {
          int k = kt * 32 + lg * 8 + e;  // 0..95: [z(64) | delta(3) | pad]
          float v = (k < 67) ? sim_w1[(64 + k) * 64 + ct * 16 + lr] : 0.0f;
          b[e] = f2bf(v);
        }
        *(bf16x8*)&bfZ[(ct * 3 + kt) * 512 + lane * 8] = b;
      }
  }

  if (blockIdx.x < 1024) {  // hb: wave handles 16 point-rows; also writes fbf
    int wave = blockIdx.x * 4 + (threadIdx.x >> 6);
    int lane = threadIdx.x & 63;
    int lr = lane & 15, lg = lane >> 4;
    int n0 = wave * 16;

    bf16x8 bf[8];  // f-part B frags (sim_w1 is L2-hot)
#pragma unroll
    for (int ct = 0; ct < 4; ++ct)
#pragma unroll
      for (int kt = 0; kt < 2; ++kt) {
        bf16x8 bb;
#pragma unroll
        for (int e = 0; e < 8; ++e)
          bb[e] = f2bf(sim_w1[(kt * 32 + lg * 8 + e) * 64 + ct * 16 + lr]);
        bf[ct * 2 + kt] = bb;
      }

    bf16x8 a[2];
#pragma unroll
    for (int kt = 0; kt < 2; ++kt) {
      const float* src = &f[(long)(n0 + lr) * 64 + kt * 32 + lg * 8];
      float4 v0 = *(const float4*)src;
      float4 v1 = *(const float4*)(src + 4);
      bf16x8 t;
      t[0] = f2bf(v0.x); t[1] = f2bf(v0.y); t[2] = f2bf(v0.z); t[3] = f2bf(v0.w);
      t[4] = f2bf(v1.x); t[5] = f2bf(v1.y); t[6] = f2bf(v1.z); t[7] = f2bf(v1.w);
      a[kt] = t;
    }
    *(bf16x8*)&fbf[(long)(n0 + lr) * 64 + lg * 8] = a[0];
    *(bf16x8*)&fbf[(long)(n0 + lr) * 64 + 32 + lg * 8] = a[1];

    f32x4 acc[4] = {{0,0,0,0},{0,0,0,0},{0,0,0,0},{0,0,0,0}};
#pragma unroll
    for (int ct = 0; ct < 4; ++ct) {
      acc[ct] = MFMA(a[0], bf[ct * 2 + 0], acc[ct], 0, 0, 0);
      acc[ct] = MFMA(a[1], bf[ct * 2 + 1], acc[ct], 0, 0, 0);
    }
    float b10 = sim_b1[lr], b11 = sim_b1[16 + lr];
    float b12 = sim_b1[32 + lr], b13 = sim_b1[48 + lr];
#pragma unroll
    for (int e = 0; e < 4; ++e) {
      // HBt packed: [n][lr*4 + ct] so pair reads hb[0..3] as one 8B load
      unsigned lo = (unsigned)(unsigned short)f2bf(acc[0][e] + b10)
                  | ((unsigned)(unsigned short)f2bf(acc[1][e] + b11) << 16);
      unsigned hi = (unsigned)(unsigned short)f2bf(acc[2][e] + b12)
                  | ((unsigned)(unsigned short)f2bf(acc[3][e] + b13) << 16);
      *(uint2*)&HBt[(long)(n0 + lg * 4 + e) * 64 + lr * 4] = make_uint2(lo, hi);
    }
  }
}

// ---- pair: preload all tiles -> MFMA all -> batched softmax -> records ----
#define TPW 4
__global__ __launch_bounds__(256) void pair_kernel(
    const float* __restrict__ pts, const unsigned short* __restrict__ zbf,
    const float* __restrict__ centers, const int* __restrict__ cand_idx,
    const float* __restrict__ sim_w2, const short* __restrict__ bfZ,
    const unsigned short* __restrict__ HBt,
    int* __restrict__ cursor, unsigned* __restrict__ rec)
{
  int wave = (blockIdx.x * 256 + threadIdx.x) >> 6;
  int lane = threadIdx.x & 63;
  int lr = lane & 15, lg = lane >> 4;

  // lane owns the record of pair wave*64+lane (tile lg, row lr)
  int call = cand_idx[wave * 64 + lane];
  // NOTE: cursor atomic deliberately NOT issued here — vmem retires in order,
  // so an early returning atomic would gate every later s_waitcnt.

  bf16x8 b[12];
#pragma unroll
  for (int i = 0; i < 12; ++i) b[i] = *(const bf16x8*)&bfZ[i * 512 + lane * 8];
  float w2c[4];
#pragma unroll
  for (int ct = 0; ct < 4; ++ct) w2c[ct] = sim_w2[ct * 16 + lr];

  // ---- preload phase: ALL tiles' operands issued back-to-back ----
  int c[TPW];
  bf16x8 a0[TPW], a1[TPW], ad[TPW];
  uint2 h2[TPW];
#pragma unroll
  for (int t = 0; t < TPW; ++t) {
    c[t] = __shfl(call, t * 16 + lr, 64);
    a0[t] = *(const bf16x8*)&zbf[(long)c[t] * 64 + lg * 8];
    a1[t] = *(const bf16x8*)&zbf[(long)c[t] * 64 + 32 + lg * 8];
    h2[t] = *(const uint2*)&HBt[((long)(wave * TPW + t) * 2 + (lg >> 1)) * 64 + lr * 4];
    bf16x8 tt = {0, 0, 0, 0, 0, 0, 0, 0};
    if (lg == 0) {
      int n = (wave * TPW + t) * 2 + (lr >> 3);
      tt[0] = f2bf(pts[n * 3 + 0] - centers[c[t] * 3 + 0]);
      tt[1] = f2bf(pts[n * 3 + 1] - centers[c[t] * 3 + 1]);
      tt[2] = f2bf(pts[n * 3 + 2] - centers[c[t] * 3 + 2]);
    }
    ad[t] = tt;
  }

  // ---- MFMA + w2-dot phase ----
  f32x4 part[TPW];
#pragma unroll
  for (int t = 0; t < TPW; ++t) {
    f32x4 acc[4] = {{0,0,0,0},{0,0,0,0},{0,0,0,0},{0,0,0,0}};
#pragma unroll
    for (int ct = 0; ct < 4; ++ct) {
      acc[ct] = MFMA(a0[t], b[ct * 3 + 0], acc[ct], 0, 0, 0);
      acc[ct] = MFMA(a1[t], b[ct * 3 + 1], acc[ct], 0, 0, 0);
      acc[ct] = MFMA(ad[t], b[ct * 3 + 2], acc[ct], 0, 0, 0);
    }
    float hb[4];
    hb[0] = bf2f((unsigned short)(h2[t].x));
    hb[1] = bf2f((unsigned short)(h2[t].x >> 16));
    hb[2] = bf2f((unsigned short)(h2[t].y));
    hb[3] = bf2f((unsigned short)(h2[t].y >> 16));
    f32x4 p = {0.f, 0.f, 0.f, 0.f};
#pragma unroll
    for (int ct = 0; ct < 4; ++ct)
#pragma unroll
      for (int e = 0; e < 4; ++e)
        p[e] = fmaf(fmaxf(acc[ct][e] + hb[ct], 0.0f), w2c[ct], p[e]);
    part[t] = p;
  }

  // ---- batched softmax phase (4 independent chains) ----
  float wrow[TPW];
#pragma unroll
  for (int t = 0; t < TPW; ++t) {
    f32x4 p = part[t];
#pragma unroll
    for (int m = 1; m <= 8; m <<= 1)
#pragma unroll
      for (int e = 0; e < 4; ++e) p[e] += __shfl_xor(p[e], m, 64);
    float other[4];
#pragma unroll
    for (int e = 0; e < 4; ++e) other[e] = __shfl_xor(p[e], 16, 64);
    float mx = p[0];
#pragma unroll
    for (int e = 1; e < 4; ++e) mx = fmaxf(mx, p[e]);
#pragma unroll
    for (int e = 0; e < 4; ++e) mx = fmaxf(mx, other[e]);
    float ex[4], se = 0.f, so = 0.f;
#pragma unroll
    for (int e = 0; e < 4; ++e) {
      ex[e] = __expf((p[e] - mx) * (1.0f / 0.3f));
      se += ex[e];
      so += __expf((other[e] - mx) * (1.0f / 0.3f));
    }
    float inv = 1.0f / (se + so);
    // lane r (0..15): weight of MFMA row r (= ex[r&3]*inv from lane (r>>2)*16)
    int srcl = (lane >> 2) << 4;
    float t0 = __shfl(ex[0] * inv, srcl, 64);
    float t1 = __shfl(ex[1] * inv, srcl, 64);
    float t2 = __shfl(ex[2] * inv, srcl, 64);
    float t3 = __shfl(ex[3] * inv, srcl, 64);
    int esel = lane & 3;
    wrow[t] = esel == 0 ? t0 : esel == 1 ? t1 : esel == 2 ? t2 : t3;
  }

  // ---- epilogue: cursor atomic (tail latency only), route weight, record ----
  int slot = atomicAdd(&cursor[call], 1);

  float v0 = __shfl(wrow[0], lr, 64);
  float v1 = __shfl(wrow[1], lr, 64);
  float v2 = __shfl(wrow[2], lr, 64);
  float v3 = __shfl(wrow[3], lr, 64);
  float wv = lg == 0 ? v0 : lg == 1 ? v1 : lg == 2 ? v2 : v3;

  if (slot < CAP) {
    int n_pt = wave * 8 + 2 * lg + (lr >> 3);
    unsigned short wh = __half_as_ushort(__float2half(wv));
    rec[(long)call * CAP + slot] = ((unsigned)n_pt << 16) | (unsigned)wh;
  }
}

// ---- gather: msg[v] = (Sum w*f[n]) / (Sum w + eps); msg ALIASES rec rows ----
__global__ __launch_bounds__(256) void gather_kernel(
    const unsigned* __restrict__ rec, const int* __restrict__ cursor,
    const unsigned short* __restrict__ fbf, unsigned short* __restrict__ msg_bf,
    int mvox)
{
  int tid = blockIdx.x * 256 + threadIdx.x;
  int row = tid >> 2, seg = tid & 3;  // 4 threads per voxel, 16 cols each
  if (row >= mvox) return;

  int cnt = cursor[row];
  cnt = cnt < CAP ? cnt : CAP;
  const unsigned* rp = &rec[(long)row * CAP];

  float acc[16];
#pragma unroll
  for (int j = 0; j < 16; ++j) acc[j] = 0.f;
  float ws = 0.f;

  for (int i0 = 0; i0 < cnt; i0 += 4) {   // rec row chunked 4-wide: fbf loads overlap
    uint4 r4 = *(const uint4*)&rp[i0];
    unsigned rr0 = r4.x, rr1 = r4.y, rr2 = r4.z, rr3 = r4.w;
#pragma unroll
    for (int j = 0; j < 4; ++j) {
      unsigned r = j == 0 ? rr0 : j == 1 ? rr1 : j == 2 ? rr2 : rr3;
      if (i0 + j < cnt) {
        float w = __half2float(__ushort_as_half((unsigned short)(r & 0xffffu)));
        int n = r >> 16;
        ws += w;
        const u16x8* fp = (const u16x8*)&fbf[(long)n * 64 + seg * 16];
        u16x8 f0 = fp[0], f1 = fp[1];
#pragma unroll
        for (int k = 0; k < 8; ++k) {
          acc[k]     = fmaf(w, bf2f(f0[k]), acc[k]);
          acc[8 + k] = fmaf(w, bf2f(f1[k]), acc[8 + k]);
        }
      }
    }
  }
  float inv = 1.0f / (ws + 1e-6f);
  u16x8 o0, o1;
#pragma unroll
  for (int j = 0; j < 8; ++j) {
    o0[j] = (unsigned short)f2bf(acc[j] * inv);
    o1[j] = (unsigned short)f2bf(acc[8 + j] * inv);
  }
  // writes land in this voxel's own (already consumed) rec row
  *(u16x8*)&msg_bf[(long)row * 64 + seg * 16] = o0;
  *(u16x8*)&msg_bf[(long)row * 64 + seg * 16 + 8] = o1;
}

// ---- Stage 2: gate MLP + GRU; two-pass; waves_per_eu(2) = min-only ----
#define GST 136
#define WST 72

__global__ __launch_bounds__(512)
__attribute__((amdgpu_waves_per_eu(2)))
void stage2(
    const unsigned short* __restrict__ zbf,
    const float* __restrict__ gate_w1, const float* __restrict__ gate_b1,
    const float* __restrict__ gate_w2, const float* __restrict__ gate_b2,
    const float* __restrict__ W_ih, const float* __restrict__ W_hh,
    const float* __restrict__ b_ih, const float* __restrict__ b_hh,
    const unsigned short* __restrict__ msg_bf,
    float* __restrict__ out, int ntiles)
{
  __shared__ short G1t[64 * GST];
  __shared__ short Wih_l[192 * WST];
  __shared__ short Whh_l[192 * WST];
  __shared__ float gb1s[64], gw2s[64], bihs[192], bhhs[192];
  __shared__ float gb2s;

  int t = threadIdx.x;
  for (int s = t; s < 64 * 128; s += 512) {
    int j = s & 63, k = s >> 6;
    G1t[j * GST + k] = f2bf(gate_w1[s]);
  }
  for (int s = t; s < 192 * 64; s += 512) {
    int j = s >> 6, k = s & 63;
    Wih_l[j * WST + k] = f2bf(W_ih[s]);
    Whh_l[j * WST + k] = f2bf(W_hh[s]);
  }
  if (t < 64) { gb1s[t] = gate_b1[t]; gw2s[t] = gate_w2[t]; }
  if (t < 192) { bihs[t] = b_ih[t]; bhhs[t] = b_hh[t]; }
  if (t == 0) gb2s = gate_b2[0];
  __syncthreads();

  int wid = t >> 6, lane = t & 63;
  int lr = lane & 15, lg = lane >> 4;

#pragma unroll 1
  for (int tile = blockIdx.x; tile < ntiles; tile += gridDim.x) {
    int rowbase = tile * 128 + wid * 16;
    long abase = (long)(rowbase + lr) * 64;
    bf16x8 a0 = *(const bf16x8*)&zbf[abase + lg * 8];
    bf16x8 a1 = *(const bf16x8*)&zbf[abase + 32 + lg * 8];
    bf16x8 a2 = *(const bf16x8*)&msg_bf[abase + lg * 8];
    bf16x8 a3 = *(const bf16x8*)&msg_bf[abase + 32 + lg * 8];

    // ---- pass 1: gate (only au live per ct) ----
    f32x4 usum = {0.f, 0.f, 0.f, 0.f};
#pragma unroll 1
    for (int ct = 0; ct < 4; ++ct) {
      f32x4 au = {0, 0, 0, 0};
      au = MFMA(a0, *(const bf16x8*)&G1t[(ct * 16 + lr) * GST +  0 + lg * 8], au, 0, 0, 0);
      au = MFMA(a1, *(const bf16x8*)&G1t[(ct * 16 + lr) * GST + 32 + lg * 8], au, 0, 0, 0);
      au = MFMA(a2, *(const bf16x8*)&G1t[(ct * 16 + lr) * GST + 64 + lg * 8], au, 0, 0, 0);
      au = MFMA(a3, *(const bf16x8*)&G1t[(ct * 16 + lr) * GST + 96 + lg * 8], au, 0, 0, 0);
      int c = ct * 16 + lr;
#pragma unroll
      for (int e = 0; e < 4; ++e)
        usum[e] += fmaxf(au[e] + gb1s[c], 0.0f) * gw2s[c];
    }
#pragma unroll
    for (int m = 1; m <= 8; m <<= 1)
#pragma unroll
      for (int e = 0; e < 4; ++e) {
        float v = usum[e];
        usum[e] = v + __shfl_xor(v, m, 64);
      }
    float gate[4];
#pragma unroll
    for (int e = 0; e < 4; ++e) gate[e] = sigm(usum[e] + gb2s);

    // ---- pass 2: GRU, write out immediately per ct ----
#pragma unroll 1
    for (int ct = 0; ct < 4; ++ct) {
      f32x4 air = {0,0,0,0}, aiz = {0,0,0,0}, ain = {0,0,0,0};
      f32x4 ahr = {0,0,0,0}, ahz = {0,0,0,0}, ahn = {0,0,0,0};
#pragma unroll
      for (int k2 = 0; k2 < 2; ++k2) {
        bf16x8 amg = k2 ? a3 : a2;
        bf16x8 az_ = k2 ? a1 : a0;
        int ko = k2 * 32 + lg * 8;
        air = MFMA(amg, *(const bf16x8*)&Wih_l[(      ct * 16 + lr) * WST + ko], air, 0, 0, 0);
        aiz = MFMA(amg, *(const bf16x8*)&Wih_l[( 64 + ct * 16 + lr) * WST + ko], aiz, 0, 0, 0);
        ain = MFMA(amg, *(const bf16x8*)&Wih_l[(128 + ct * 16 + lr) * WST + ko], ain, 0, 0, 0);
        ahr = MFMA(az_, *(const bf16x8*)&Whh_l[(      ct * 16 + lr) * WST + ko], ahr, 0, 0, 0);
        ahz = MFMA(az_, *(const bf16x8*)&Whh_l[( 64 + ct * 16 + lr) * WST + ko], ahz, 0, 0, 0);
        ahn = MFMA(az_, *(const bf16x8*)&Whh_l[(128 + ct * 16 + lr) * WST + ko], ahn, 0, 0, 0);
      }
      int c = ct * 16 + lr;
#pragma unroll
      for (int e = 0; e < 4; ++e) {
        float zv = bf2f(zbf[(long)(rowbase + lg * 4 + e) * 64 + c]);
        float rr = sigm(air[e] + bihs[c] + ahr[e] + bhhs[c]);
        float zg = sigm(aiz[e] + bihs[64 + c] + ahz[e] + bhhs[64 + c]);
        float nn = tanhf(ain[e] + bihs[128 + c] + rr * (ahn[e] + bhhs[128 + c]));
        float hnew = (1.0f - zg) * nn + zg * zv;
        out[(long)(rowbase + lg * 4 + e) * 64 + c] = zv + gate[e] * (hnew - zv);
      }
    }
  }
}

extern "C" void kernel_launch(void* const* d_in, const int* in_sizes, int n_in,
                              void* d_out, int out_size, void* d_ws, size_t ws_size,
                              hipStream_t stream) {
  const float* f_pts   = (const float*)d_in[0];
  const float* pts     = (const float*)d_in[1];
  const float* z_lat   = (const float*)d_in[2];
  const float* centers = (const float*)d_in[3];
  const int*   cand    = (const int*)d_in[4];
  const float* sim_w1  = (const float*)d_in[5];
  const float* sim_b1  = (const float*)d_in[6];
  const float* sim_w2  = (const float*)d_in[7];
  // d_in[8] = sim_b2: uniform softmax shift, unused
  const float* gate_w1 = (const float*)d_in[9];
  const float* gate_b1 = (const float*)d_in[10];
  const float* gate_w2 = (const float*)d_in[11];
  const float* gate_b2 = (const float*)d_in[12];
  const float* W_ih    = (const float*)d_in[13];
  const float* W_hh    = (const float*)d_in[14];
  const float* b_ih    = (const float*)d_in[15];
  const float* b_hh    = (const float*)d_in[16];

  int N = in_sizes[0] / 64;
  int M = in_sizes[2] / 64;

  int* cursor = (int*)d_ws;                                        // M i32
  unsigned* rec = (unsigned*)(cursor + M);                         // M*CAP u32
  unsigned short* msg_bf = (unsigned short*)rec;                   // alias: rec consumed by gather
  unsigned short* zbf = (unsigned short*)(rec + (size_t)M * CAP);  // M*64 bf16 (live thru stage2)
  unsigned short* fbf = zbf + (size_t)M * 64;                      // N*64 bf16
  unsigned short* HBt = fbf + (size_t)N * 64;                      // N*64 bf16 (ct-packed)
  short* bfZ = (short*)(HBt + (size_t)N * 64);                     // 12*512 bf16

  prep_kernel<<<2048, 256, 0, stream>>>(z_lat, f_pts, sim_w1, sim_b1,
                                        zbf, fbf, HBt, cursor, bfZ, M);

  int nwaves = (N * 8) / (16 * TPW);                               // 8192 waves
  pair_kernel<<<nwaves / 4, 256, 0, stream>>>(pts, zbf, centers, cand,
                                              sim_w2, bfZ, HBt, cursor, rec);

  gather_kernel<<<(M * 4) / 256, 256, 0, stream>>>(rec, cursor, fbf, msg_bf, M);

  int ntiles = M / 128;
  stage2<<<512, 512, 0, stream>>>(zbf, gate_w1, gate_b1, gate_w2, gate_b2,
                                  W_ih, W_hh, b_ih, b_hh, msg_bf,
                                  (float*)d_out, ntiles);
}